// Round 1
// baseline (832.389 us; speedup 1.0000x reference)
//
#include <hip/hip_runtime.h>
#include <stdint.h>

#define NROWS 50000
#define DIM   512
#define ODIM  256
#define FOLDS 5
#define FOLD  10000
#define NTR   40000
#define CHK   1280
#define NCHUNK 8

__constant__ float c_lam[5] = {0.01f, 0.1f, 1.0f, 10.0f, 100.0f};

typedef __attribute__((ext_vector_type(8))) short short8;
typedef __attribute__((ext_vector_type(4))) float floatx4;

__device__ __forceinline__ unsigned short f2bf(float f) {
  unsigned u = __float_as_uint(f);
  u += 0x7FFFu + ((u >> 16) & 1u);          // RNE
  return (unsigned short)(u >> 16);
}
__device__ __forceinline__ float bf2f(unsigned short h) {
  return __uint_as_float(((unsigned)h) << 16);
}

__device__ __forceinline__ float block_sum256(float v) {
  __shared__ float red[4];
  for (int off = 32; off; off >>= 1) v += __shfl_down(v, off, 64);
  if ((threadIdx.x & 63) == 0) red[threadIdx.x >> 6] = v;
  __syncthreads();
  float r = 0.f;
  if (threadIdx.x == 0) r = red[0] + red[1] + red[2] + red[3];
  return r;
}

// ---------- transpose X [50000,512] f32 -> XT [512][50000] bf16 ----------
__global__ __launch_bounds__(256) void k_tX(const float* __restrict__ X,
                                            unsigned short* __restrict__ XT) {
  __shared__ unsigned short lds[64][72];
  int n0 = blockIdx.x * 64, d0 = blockIdx.y * 64;
  int t = threadIdx.x;
  #pragma unroll
  for (int p = 0; p < 4; ++p) {
    int r = p * 16 + (t >> 4);
    int c = (t & 15) * 4;
    int n = n0 + r;
    float4 v = make_float4(0.f, 0.f, 0.f, 0.f);
    if (n < NROWS) v = *(const float4*)(X + (size_t)n * DIM + d0 + c);
    lds[c + 0][r] = f2bf(v.x);
    lds[c + 1][r] = f2bf(v.y);
    lds[c + 2][r] = f2bf(v.z);
    lds[c + 3][r] = f2bf(v.w);
  }
  __syncthreads();
  #pragma unroll
  for (int p = 0; p < 2; ++p) {
    int d = p * 32 + (t >> 3);
    int nc = (t & 7) * 8;
    if (n0 + nc < NROWS) {
      uint4 v = *(const uint4*)&lds[d][nc];
      *(uint4*)(XT + (size_t)(d0 + d) * NROWS + n0 + nc) = v;
    }
  }
}

// ---------- per-fold column sums of X (from XT) ----------
__global__ __launch_bounds__(64) void k_sumX(const unsigned short* __restrict__ XT,
                                             float* __restrict__ sumX_f) {
  int seg = blockIdx.x;            // k*512 + d
  int k = seg / DIM, d = seg % DIM;
  const unsigned short* row = XT + (size_t)d * NROWS + k * FOLD;
  float s = 0.f;
  for (int i = threadIdx.x * 4; i < FOLD; i += 64 * 4) {
    ushort4 v = *(const ushort4*)(row + i);
    s += bf2f(v.x) + bf2f(v.y) + bf2f(v.z) + bf2f(v.w);
  }
  for (int off = 32; off; off >>= 1) s += __shfl_down(s, off, 64);
  if (threadIdx.x == 0) sumX_f[seg] = s;
}

// ---------- per-fold sums of Y and sum of Y^2 (f32 exact-ish) ----------
__global__ __launch_bounds__(256) void k_sumY(const float* __restrict__ Y,
                                              float* __restrict__ sumY_f,
                                              float* __restrict__ yy_f) {
  int k = blockIdx.x, ch = blockIdx.y;
  int o = threadIdx.x;
  int nbeg = k * FOLD + ch * 625, nend = nbeg + 625;
  float s = 0.f, q = 0.f;
  for (int n = nbeg; n < nend; ++n) {
    float v = Y[(size_t)n * ODIM + o];
    s += v; q += v * v;
  }
  atomicAdd(&sumY_f[k * ODIM + o], s);
  float qs = block_sum256(q);
  if (threadIdx.x == 0) atomicAdd(&yy_f[k], qs);
}

// ---------- MFMA inner step: D += A*B over K=64 staged in LDS ----------
__device__ __forceinline__ void mfma_step(const unsigned short (*A)[72],
                                          const unsigned short (*B)[72],
                                          int wm, int wn, int lane,
                                          floatx4 acc[4][4]) {
  int fr = lane & 15;
  int fq = (lane >> 4) * 8;
  #pragma unroll
  for (int kk = 0; kk < 64; kk += 32) {
    short8 af[4], bfv[4];
    #pragma unroll
    for (int mt = 0; mt < 4; ++mt)
      af[mt] = *(const short8*)&A[wm + mt * 16 + fr][kk + fq];
    #pragma unroll
    for (int nt = 0; nt < 4; ++nt)
      bfv[nt] = *(const short8*)&B[wn + nt * 16 + fr][kk + fq];
    #pragma unroll
    for (int mt = 0; mt < 4; ++mt)
      #pragma unroll
      for (int nt = 0; nt < 4; ++nt)
        acc[mt][nt] = __builtin_amdgcn_mfma_f32_16x16x32_bf16(af[mt], bfv[nt], acc[mt][nt], 0, 0, 0);
  }
}

// ---------- per-fold Gram X^T X  (atomic split-K) ----------
__global__ __launch_bounds__(256, 2) void k_gram_xx(const unsigned short* __restrict__ XT,
                                                    float* __restrict__ xxT) {
  __shared__ unsigned short Ab[128][72];
  __shared__ unsigned short Bb[128][72];
  int ti = blockIdx.x & 3, tj = blockIdx.x >> 2;
  int f = blockIdx.y, c = blockIdx.z;
  int i0 = ti * 128, j0 = tj * 128;
  int kbeg = c * CHK, kend = min(FOLD, kbeg + CHK);
  size_t basek = (size_t)f * FOLD;
  int t = threadIdx.x, lane = t & 63, w = t >> 6;
  int wm = (w & 1) * 64, wn = (w >> 1) * 64;
  floatx4 acc[4][4];
  #pragma unroll
  for (int a = 0; a < 4; ++a)
    #pragma unroll
    for (int b = 0; b < 4; ++b) acc[a][b] = (floatx4)0.f;
  for (int ks = kbeg; ks < kend; ks += 64) {
    #pragma unroll
    for (int q = 0; q < 4; ++q) {
      int lin = t + q * 256;
      int row = lin >> 3, col8 = (lin & 7) * 8;
      int gk = ks + col8;
      uint4 va = make_uint4(0, 0, 0, 0), vb = va;
      if (gk < kend) {
        va = *(const uint4*)(XT + (size_t)(i0 + row) * NROWS + basek + gk);
        vb = *(const uint4*)(XT + (size_t)(j0 + row) * NROWS + basek + gk);
      }
      *(uint4*)&Ab[row][col8] = va;
      *(uint4*)&Bb[row][col8] = vb;
    }
    __syncthreads();
    mfma_step(Ab, Bb, wm, wn, lane, acc);
    __syncthreads();
  }
  float* out = xxT + (size_t)f * DIM * DIM;
  #pragma unroll
  for (int mt = 0; mt < 4; ++mt)
    #pragma unroll
    for (int nt = 0; nt < 4; ++nt)
      #pragma unroll
      for (int i = 0; i < 4; ++i) {
        int row = i0 + wm + mt * 16 + ((lane >> 4) * 4 + i);
        int col = j0 + wn + nt * 16 + (lane & 15);
        atomicAdd(&out[row * DIM + col], acc[mt][nt][i]);
      }
}

// ---------- per-fold cross Gram (Y^T X), output [k][o][d] ----------
__global__ __launch_bounds__(256, 2) void k_gram_xy(const unsigned short* __restrict__ XT,
                                                    const float* __restrict__ Y,
                                                    float* __restrict__ xyT) {
  __shared__ unsigned short Ab[128][72];   // [o][n]
  __shared__ unsigned short Bb[128][72];   // [d][n]
  int ti = blockIdx.x & 1, tj = blockIdx.x >> 1;
  int f = blockIdx.y, c = blockIdx.z;
  int i0 = ti * 128, j0 = tj * 128;
  int kbeg = c * CHK, kend = min(FOLD, kbeg + CHK);
  int basek = f * FOLD;
  int t = threadIdx.x, lane = t & 63, w = t >> 6;
  int wm = (w & 1) * 64, wn = (w >> 1) * 64;
  floatx4 acc[4][4];
  #pragma unroll
  for (int a = 0; a < 4; ++a)
    #pragma unroll
    for (int b = 0; b < 4; ++b) acc[a][b] = (floatx4)0.f;
  for (int ks = kbeg; ks < kend; ks += 64) {
    #pragma unroll
    for (int q = 0; q < 8; ++q) {                       // stage Y -> transposed bf16
      int lin = t + q * 256;
      int nr = lin >> 5, c4 = (lin & 31) * 4;
      int gk = ks + nr;
      float4 v = make_float4(0.f, 0.f, 0.f, 0.f);
      if (gk < kend) v = *(const float4*)(Y + (size_t)(basek + gk) * ODIM + i0 + c4);
      Ab[c4 + 0][nr] = f2bf(v.x);
      Ab[c4 + 1][nr] = f2bf(v.y);
      Ab[c4 + 2][nr] = f2bf(v.z);
      Ab[c4 + 3][nr] = f2bf(v.w);
    }
    #pragma unroll
    for (int q = 0; q < 4; ++q) {                       // stage XT rows (d)
      int lin = t + q * 256;
      int row = lin >> 3, col8 = (lin & 7) * 8;
      int gk = ks + col8;
      uint4 vb = make_uint4(0, 0, 0, 0);
      if (gk < kend) vb = *(const uint4*)(XT + (size_t)(j0 + row) * NROWS + basek + gk);
      *(uint4*)&Bb[row][col8] = vb;
    }
    __syncthreads();
    mfma_step(Ab, Bb, wm, wn, lane, acc);
    __syncthreads();
  }
  float* out = xyT + (size_t)f * ODIM * DIM;
  #pragma unroll
  for (int mt = 0; mt < 4; ++mt)
    #pragma unroll
    for (int nt = 0; nt < 4; ++nt)
      #pragma unroll
      for (int i = 0; i < 4; ++i) {
        int row = i0 + wm + mt * 16 + ((lane >> 4) * 4 + i);
        int col = j0 + wn + nt * 16 + (lane & 15);
        atomicAdd(&out[row * DIM + col], acc[mt][nt][i]);
      }
}

// ---------- train means (5 LOO + full) ----------
__global__ void k_means(const float* __restrict__ sumX_f, const float* __restrict__ sumY_f,
                        float* __restrict__ muX, float* __restrict__ muY) {
  int g = blockIdx.x * 256 + threadIdx.x;
  if (g < 6 * DIM) {
    int k = g / DIM, d = g % DIM;
    float s = 0.f;
    #pragma unroll
    for (int kk = 0; kk < 5; ++kk) s += sumX_f[kk * DIM + d];
    muX[g] = (k < 5) ? (s - sumX_f[k * DIM + d]) / (float)NTR : s / (float)NROWS;
  } else {
    int g2 = g - 6 * DIM;
    int k = g2 / ODIM, o = g2 % ODIM;
    float s = 0.f;
    #pragma unroll
    for (int kk = 0; kk < 5; ++kk) s += sumY_f[kk * ODIM + o];
    muY[g2] = (k < 5) ? (s - sumY_f[k * ODIM + o]) / (float)NTR : s / (float)NROWS;
  }
}

// ---------- assemble A_k (LOO centered Gram, bf16) + Gv (val Gram, bf16) ----------
__global__ void k_asmA(const float* __restrict__ xxT, const float* __restrict__ muX,
                       unsigned short* __restrict__ Abf, unsigned short* __restrict__ Gv) {
  size_t g = (size_t)blockIdx.x * 256 + threadIdx.x;     // < 6*512*512
  int k = (int)(g / (DIM * DIM));
  int r = (int)(g % (DIM * DIM));
  int d = r / DIM, e = r % DIM;
  float s = 0.f;
  #pragma unroll
  for (int kk = 0; kk < 5; ++kk) s += xxT[(size_t)kk * DIM * DIM + r];
  float v;
  if (k < 5) {
    float own = xxT[(size_t)k * DIM * DIM + r];
    v = s - own - (float)NTR * muX[k * DIM + d] * muX[k * DIM + e];
    Gv[(size_t)k * DIM * DIM + r] = f2bf(own);
  } else {
    v = s - (float)NROWS * muX[5 * DIM + d] * muX[5 * DIM + e];
  }
  Abf[g] = f2bf(v);
}

// ---------- assemble B_k^T [k][o][d] f32 and init x0 for all 30 systems ----------
__global__ void k_asmB(const float* __restrict__ xyT, const float* __restrict__ muX,
                       const float* __restrict__ muY, float* __restrict__ BT,
                       unsigned short* __restrict__ x0) {
  int g = blockIdx.x * 256 + threadIdx.x;                // < 6*256*512
  int k = g / (ODIM * DIM);
  int r = g % (ODIM * DIM);
  int o = r / DIM, d = r % DIM;
  float s = 0.f;
  #pragma unroll
  for (int kk = 0; kk < 5; ++kk) s += xyT[(size_t)kk * ODIM * DIM + r];
  float v;
  if (k < 5) v = s - xyT[(size_t)k * ODIM * DIM + r] - (float)NTR * muY[k * ODIM + o] * muX[k * DIM + d];
  else       v = s - (float)NROWS * muY[5 * ODIM + o] * muX[5 * DIM + d];
  BT[g] = v;
  float halfsum = (k < 5) ? 40750.f : 50750.f;           // (a+b)/2 spectral midpoint
  #pragma unroll
  for (int l = 0; l < 5; ++l) {
    float th = halfsum + c_lam[l];
    x0[(size_t)(l * 6 + k) * (ODIM * DIM) + r] = f2bf(v / th);
  }
}

// ---------- one Richardson sweep over all 30 systems ----------
__global__ __launch_bounds__(256, 2) void k_rich(const unsigned short* __restrict__ xin,
                                                 unsigned short* __restrict__ xout,
                                                 const unsigned short* __restrict__ Abf,
                                                 const float* __restrict__ BT) {
  __shared__ unsigned short Xb[128][72];
  __shared__ unsigned short Mb[128][72];
  int tile = blockIdx.x;
  int o0 = (tile & 1) * 128, d0 = (tile >> 1) * 128;
  int s = blockIdx.y;
  int k = s % 6, l = s / 6;
  float lam = c_lam[l];
  float absum = (k < 5) ? 81500.f : 101500.f;
  float alpha = 2.f / (absum + 2.f * lam);
  const unsigned short* xs = xin + (size_t)s * ODIM * DIM;
  const unsigned short* Am = Abf + (size_t)k * DIM * DIM;
  int t = threadIdx.x, lane = t & 63, w = t >> 6;
  int wm = (w & 1) * 64, wn = (w >> 1) * 64;
  floatx4 acc[4][4];
  #pragma unroll
  for (int a = 0; a < 4; ++a)
    #pragma unroll
    for (int b = 0; b < 4; ++b) acc[a][b] = (floatx4)0.f;
  for (int ks = 0; ks < DIM; ks += 64) {
    #pragma unroll
    for (int q = 0; q < 4; ++q) {
      int lin = t + q * 256;
      int row = lin >> 3, col8 = (lin & 7) * 8;
      *(uint4*)&Xb[row][col8] = *(const uint4*)(xs + (size_t)(o0 + row) * DIM + ks + col8);
      *(uint4*)&Mb[row][col8] = *(const uint4*)(Am + (size_t)(d0 + row) * DIM + ks + col8);
    }
    __syncthreads();
    mfma_step(Xb, Mb, wm, wn, lane, acc);
    __syncthreads();
  }
  const float* Bk = BT + (size_t)k * ODIM * DIM;
  unsigned short* xo = xout + (size_t)s * ODIM * DIM;
  #pragma unroll
  for (int mt = 0; mt < 4; ++mt)
    #pragma unroll
    for (int nt = 0; nt < 4; ++nt)
      #pragma unroll
      for (int i = 0; i < 4; ++i) {
        int ro = o0 + wm + mt * 16 + ((lane >> 4) * 4 + i);
        int cd = d0 + wn + nt * 16 + (lane & 15);
        int idx = ro * DIM + cd;
        float xold = bf2f(xs[idx]);
        float r = Bk[idx] - acc[mt][nt][i] - lam * xold;
        xo[idx] = f2bf(xold + alpha * r);
      }
}

// ---------- tr(W^T Gv W) via GEMM + dot, atomic per (l,k) ----------
__global__ __launch_bounds__(256, 2) void k_loss_big(const unsigned short* __restrict__ x,
                                                     const unsigned short* __restrict__ Gv,
                                                     float* __restrict__ SSEb) {
  __shared__ unsigned short Xb[128][72];
  __shared__ unsigned short Mb[128][72];
  int tile = blockIdx.x;
  int o0 = (tile & 1) * 128, d0 = (tile >> 1) * 128;
  int s25 = blockIdx.y;
  int k = s25 % 5, l = s25 / 5;
  int s = l * 6 + k;
  const unsigned short* xs = x + (size_t)s * ODIM * DIM;
  const unsigned short* Gm = Gv + (size_t)k * DIM * DIM;
  int t = threadIdx.x, lane = t & 63, w = t >> 6;
  int wm = (w & 1) * 64, wn = (w >> 1) * 64;
  floatx4 acc[4][4];
  #pragma unroll
  for (int a = 0; a < 4; ++a)
    #pragma unroll
    for (int b = 0; b < 4; ++b) acc[a][b] = (floatx4)0.f;
  for (int ks = 0; ks < DIM; ks += 64) {
    #pragma unroll
    for (int q = 0; q < 4; ++q) {
      int lin = t + q * 256;
      int row = lin >> 3, col8 = (lin & 7) * 8;
      *(uint4*)&Xb[row][col8] = *(const uint4*)(xs + (size_t)(o0 + row) * DIM + ks + col8);
      *(uint4*)&Mb[row][col8] = *(const uint4*)(Gm + (size_t)(d0 + row) * DIM + ks + col8);
    }
    __syncthreads();
    mfma_step(Xb, Mb, wm, wn, lane, acc);
    __syncthreads();
  }
  float part = 0.f;
  #pragma unroll
  for (int mt = 0; mt < 4; ++mt)
    #pragma unroll
    for (int nt = 0; nt < 4; ++nt)
      #pragma unroll
      for (int i = 0; i < 4; ++i) {
        int ro = o0 + wm + mt * 16 + ((lane >> 4) * 4 + i);
        int cd = d0 + wn + nt * 16 + (lane & 15);
        part += acc[mt][nt][i] * bf2f(xs[ro * DIM + cd]);
      }
  float tot = block_sum256(part);
  if (threadIdx.x == 0) atomicAdd(&SSEb[s25], tot);
}

// ---------- linear/const SSE terms per (l,k) ----------
__global__ __launch_bounds__(256) void k_loss_small(const unsigned short* __restrict__ x,
                                                    const float* __restrict__ xyT,
                                                    const float* __restrict__ muX,
                                                    const float* __restrict__ muY,
                                                    const float* __restrict__ sumX_f,
                                                    const float* __restrict__ sumY_f,
                                                    const float* __restrict__ yy_f,
                                                    float* __restrict__ SSEs) {
  __shared__ float lmu[DIM];
  __shared__ float lsx[DIM];
  int s25 = blockIdx.x;
  int k = s25 % 5, l = s25 / 5;
  int sidx = l * 6 + k;
  int o = threadIdx.x;
  lmu[o] = muX[k * DIM + o];       lmu[o + 256] = muX[k * DIM + o + 256];
  lsx[o] = sumX_f[k * DIM + o];    lsx[o + 256] = sumX_f[k * DIM + o + 256];
  __syncthreads();
  const unsigned short* xr = x + (size_t)sidx * ODIM * DIM + (size_t)o * DIM;
  const float* cv = xyT + (size_t)k * ODIM * DIM + (size_t)o * DIM;
  float t1 = 0.f, t2 = 0.f, trc = 0.f;
  for (int d = 0; d < DIM; d += 4) {
    ushort4 xv = *(const ushort4*)(xr + d);
    float4 cf = *(const float4*)(cv + d);
    float a0 = bf2f(xv.x), a1 = bf2f(xv.y), a2 = bf2f(xv.z), a3 = bf2f(xv.w);
    t1 += a0 * lsx[d] + a1 * lsx[d + 1] + a2 * lsx[d + 2] + a3 * lsx[d + 3];
    t2 += a0 * lmu[d] + a1 * lmu[d + 1] + a2 * lmu[d + 2] + a3 * lmu[d + 3];
    trc += a0 * cf.x + a1 * cf.y + a2 * cf.z + a3 * cf.w;
  }
  float b = muY[k * ODIM + o] - t2;
  float syv = sumY_f[k * ODIM + o];
  float part = 2.f * b * t1 + (float)FOLD * b * b - 2.f * trc - 2.f * b * syv;
  float tot = block_sum256(part);
  if (threadIdx.x == 0) SSEs[s25] = tot + yy_f[k];
}

// ---------- losses + argmin ----------
__global__ void k_loss_final(const float* __restrict__ SSEs, const float* __restrict__ SSEb,
                             float* __restrict__ out, int* __restrict__ aidx) {
  if (threadIdx.x == 0) {
    float best = 1e30f; int bi = 0;
    for (int l = 0; l < 5; ++l) {
      float s = 0.f;
      for (int k = 0; k < 5; ++k) s += SSEs[l * 5 + k] + SSEb[l * 5 + k];
      float loss = s / (float)(FOLDS * FOLD * ODIM);
      out[131072 + 256 + l] = loss;
      if (loss < best) { best = loss; bi = l; }
    }
    aidx[0] = bi;
  }
}

// ---------- outputs ----------
__global__ void k_outW(const unsigned short* __restrict__ x, const int* __restrict__ aidx,
                       float* __restrict__ out) {
  int g = blockIdx.x * 256 + threadIdx.x;
  int s = aidx[0] * 6 + 5;
  out[g] = bf2f(x[(size_t)s * ODIM * DIM + g]);
}

__global__ __launch_bounds__(64) void k_outB(const unsigned short* __restrict__ x,
                                             const float* __restrict__ muX,
                                             const float* __restrict__ muY,
                                             const int* __restrict__ aidx,
                                             float* __restrict__ out) {
  int o = blockIdx.x, lane = threadIdx.x;
  int s = aidx[0] * 6 + 5;
  const unsigned short* xr = x + (size_t)s * ODIM * DIM + (size_t)o * DIM;
  float dsum = 0.f;
  for (int d = lane; d < DIM; d += 64) dsum += bf2f(xr[d]) * muX[5 * DIM + d];
  for (int off = 32; off; off >>= 1) dsum += __shfl_down(dsum, off, 64);
  if (lane == 0) out[131072 + o] = muY[5 * ODIM + o] - dsum;
}

extern "C" void kernel_launch(void* const* d_in, const int* in_sizes, int n_in,
                              void* d_out, int out_size, void* d_ws, size_t ws_size,
                              hipStream_t stream) {
  const float* X = (const float*)d_in[0];
  const float* Y = (const float*)d_in[1];
  float* out = (float*)d_out;
  char* ws = (char*)d_ws;
  size_t off = 0;
  auto alloc = [&](size_t bytes) {
    size_t cur = off;
    off = (off + bytes + 255) & ~(size_t)255;
    return cur;
  };
  unsigned short* XT = (unsigned short*)(ws + alloc((size_t)DIM * NROWS * 2));
  size_t zbeg = off;
  float* xxT    = (float*)(ws + alloc((size_t)5 * DIM * DIM * 4));
  float* xyT    = (float*)(ws + alloc((size_t)5 * ODIM * DIM * 4));
  float* sumY_f = (float*)(ws + alloc(5 * ODIM * 4));
  float* yy_f   = (float*)(ws + alloc(5 * 4));
  float* SSEb   = (float*)(ws + alloc(25 * 4));
  size_t zend = off;
  float* sumX_f = (float*)(ws + alloc(5 * DIM * 4));
  float* muX    = (float*)(ws + alloc(6 * DIM * 4));
  float* muY    = (float*)(ws + alloc(6 * ODIM * 4));
  unsigned short* Abf = (unsigned short*)(ws + alloc((size_t)6 * DIM * DIM * 2));
  unsigned short* Gv  = (unsigned short*)(ws + alloc((size_t)5 * DIM * DIM * 2));
  float* BT     = (float*)(ws + alloc((size_t)6 * ODIM * DIM * 4));
  unsigned short* x0 = (unsigned short*)(ws + alloc((size_t)30 * ODIM * DIM * 2));
  unsigned short* x1 = (unsigned short*)(ws + alloc((size_t)30 * ODIM * DIM * 2));
  float* SSEs   = (float*)(ws + alloc(25 * 4));
  int* aidx     = (int*)(ws + alloc(4));

  hipMemsetAsync(ws + zbeg, 0, zend - zbeg, stream);

  k_tX<<<dim3(782, 8), 256, 0, stream>>>(X, XT);
  k_sumX<<<5 * DIM, 64, 0, stream>>>(XT, sumX_f);
  k_sumY<<<dim3(5, 16), 256, 0, stream>>>(Y, sumY_f, yy_f);
  k_gram_xx<<<dim3(16, 5, NCHUNK), 256, 0, stream>>>(XT, xxT);
  k_gram_xy<<<dim3(8, 5, NCHUNK), 256, 0, stream>>>(XT, Y, xyT);
  k_means<<<18, 256, 0, stream>>>(sumX_f, sumY_f, muX, muY);
  k_asmA<<<6 * DIM * DIM / 256, 256, 0, stream>>>(xxT, muX, Abf, Gv);
  k_asmB<<<6 * ODIM * DIM / 256, 256, 0, stream>>>(xyT, muX, muY, BT, x0);
  for (int it = 0; it < 8; ++it) {
    const unsigned short* xin = (it & 1) ? x1 : x0;
    unsigned short* xout = (it & 1) ? x0 : x1;
    k_rich<<<dim3(8, 30), 256, 0, stream>>>(xin, xout, Abf, BT);
  }
  // after 8 iterations result is back in x0
  k_loss_small<<<25, 256, 0, stream>>>(x0, xyT, muX, muY, sumX_f, sumY_f, yy_f, SSEs);
  k_loss_big<<<dim3(8, 25), 256, 0, stream>>>(x0, Gv, SSEb);
  k_loss_final<<<1, 64, 0, stream>>>(SSEs, SSEb, out, aidx);
  k_outW<<<DIM * ODIM / 256 * 2 / 2, 256, 0, stream>>>(x0, aidx, out);  // 512 blocks
  k_outB<<<ODIM, 64, 0, stream>>>(x0, muX, muY, aidx, out);
}

// Round 4
// 595.704 us; speedup vs baseline: 1.3973x; 1.3973x over previous
//
#include <hip/hip_runtime.h>
#include <stdint.h>

#define NROWS 50000
#define DIM   512
#define ODIM  256
#define FOLDS 5
#define FOLD  10000
#define NTR   40000
#define CHK   1280
#define NCHUNK 8

__constant__ float c_lam[5] = {0.01f, 0.1f, 1.0f, 10.0f, 100.0f};

typedef __attribute__((ext_vector_type(8))) short short8;
typedef __attribute__((ext_vector_type(4))) float floatx4;

__device__ __forceinline__ unsigned short f2bf(float f) {
  unsigned u = __float_as_uint(f);
  u += 0x7FFFu + ((u >> 16) & 1u);          // RNE
  return (unsigned short)(u >> 16);
}
__device__ __forceinline__ float bf2f(unsigned short h) {
  return __uint_as_float(((unsigned)h) << 16);
}

__device__ __forceinline__ float block_sum256(float v) {
  __shared__ float red[4];
  for (int off = 32; off; off >>= 1) v += __shfl_down(v, off, 64);
  if ((threadIdx.x & 63) == 0) red[threadIdx.x >> 6] = v;
  __syncthreads();
  float r = 0.f;
  if (threadIdx.x == 0) r = red[0] + red[1] + red[2] + red[3];
  return r;
}

// ---------- transpose X [50000,512] f32 -> XT [512][50000] bf16 ----------
__global__ __launch_bounds__(256) void k_tX(const float* __restrict__ X,
                                            unsigned short* __restrict__ XT) {
  __shared__ unsigned short lds[64][72];
  int n0 = blockIdx.x * 64, d0 = blockIdx.y * 64;
  int t = threadIdx.x;
  #pragma unroll
  for (int p = 0; p < 4; ++p) {
    int r = p * 16 + (t >> 4);
    int c = (t & 15) * 4;
    int n = n0 + r;
    float4 v = make_float4(0.f, 0.f, 0.f, 0.f);
    if (n < NROWS) v = *(const float4*)(X + (size_t)n * DIM + d0 + c);
    lds[c + 0][r] = f2bf(v.x);
    lds[c + 1][r] = f2bf(v.y);
    lds[c + 2][r] = f2bf(v.z);
    lds[c + 3][r] = f2bf(v.w);
  }
  __syncthreads();
  #pragma unroll
  for (int p = 0; p < 2; ++p) {
    int d = p * 32 + (t >> 3);
    int nc = (t & 7) * 8;
    if (n0 + nc < NROWS) {
      uint4 v = *(const uint4*)&lds[d][nc];
      *(uint4*)(XT + (size_t)(d0 + d) * NROWS + n0 + nc) = v;
    }
  }
}

// ---------- per-fold column sums of X (from XT) ----------
__global__ __launch_bounds__(64) void k_sumX(const unsigned short* __restrict__ XT,
                                             float* __restrict__ sumX_f) {
  int seg = blockIdx.x;            // k*512 + d
  int k = seg / DIM, d = seg % DIM;
  const unsigned short* row = XT + (size_t)d * NROWS + k * FOLD;
  float s = 0.f;
  for (int i = threadIdx.x * 4; i < FOLD; i += 64 * 4) {
    ushort4 v = *(const ushort4*)(row + i);
    s += bf2f(v.x) + bf2f(v.y) + bf2f(v.z) + bf2f(v.w);
  }
  for (int off = 32; off; off >>= 1) s += __shfl_down(s, off, 64);
  if (threadIdx.x == 0) sumX_f[seg] = s;
}

// ---------- per-fold sums of Y and sum of Y^2 ----------
// grid (5, 125), 256 threads: block handles 80 rows of its fold.
// Each wave-group (4 per block) takes rows r+grp; float4 per lane covers a
// full 1 KB row per group per iteration. 625 blocks = 2500 waves.
__global__ __launch_bounds__(256) void k_sumY(const float* __restrict__ Y,
                                              float* __restrict__ sumY_f,
                                              float* __restrict__ yy_f) {
  __shared__ float sh[4][ODIM];
  int k = blockIdx.x, ch = blockIdx.y;
  int lane = threadIdx.x & 63, grp = threadIdx.x >> 6;
  int nbeg = k * FOLD + ch * 80;
  float s0 = 0.f, s1 = 0.f, s2 = 0.f, s3 = 0.f, q = 0.f;
  #pragma unroll 4
  for (int r = 0; r < 80; r += 4) {
    int n = nbeg + r + grp;
    float4 v = *(const float4*)(Y + (size_t)n * ODIM + lane * 4);
    s0 += v.x; s1 += v.y; s2 += v.z; s3 += v.w;
    q += v.x * v.x + v.y * v.y + v.z * v.z + v.w * v.w;
  }
  sh[grp][lane * 4 + 0] = s0;
  sh[grp][lane * 4 + 1] = s1;
  sh[grp][lane * 4 + 2] = s2;
  sh[grp][lane * 4 + 3] = s3;
  __syncthreads();
  int o = threadIdx.x;
  float t = sh[0][o] + sh[1][o] + sh[2][o] + sh[3][o];
  atomicAdd(&sumY_f[k * ODIM + o], t);
  float qt = block_sum256(q);
  if (threadIdx.x == 0) atomicAdd(&yy_f[k], qt);
}

// ---------- MFMA inner step: D += A*B over K=64 staged in LDS ----------
__device__ __forceinline__ void mfma_step(const unsigned short (*A)[72],
                                          const unsigned short (*B)[72],
                                          int wm, int wn, int lane,
                                          floatx4 acc[4][4]) {
  int fr = lane & 15;
  int fq = (lane >> 4) * 8;
  #pragma unroll
  for (int kk = 0; kk < 64; kk += 32) {
    short8 af[4], bfv[4];
    #pragma unroll
    for (int mt = 0; mt < 4; ++mt)
      af[mt] = *(const short8*)&A[wm + mt * 16 + fr][kk + fq];
    #pragma unroll
    for (int nt = 0; nt < 4; ++nt)
      bfv[nt] = *(const short8*)&B[wn + nt * 16 + fr][kk + fq];
    #pragma unroll
    for (int mt = 0; mt < 4; ++mt)
      #pragma unroll
      for (int nt = 0; nt < 4; ++nt)
        acc[mt][nt] = __builtin_amdgcn_mfma_f32_16x16x32_bf16(af[mt], bfv[nt], acc[mt][nt], 0, 0, 0);
  }
}

// ---------- per-fold Gram X^T X  (atomic split-K) ----------
__global__ __launch_bounds__(256, 2) void k_gram_xx(const unsigned short* __restrict__ XT,
                                                    float* __restrict__ xxT) {
  __shared__ unsigned short Ab[128][72];
  __shared__ unsigned short Bb[128][72];
  int ti = blockIdx.x & 3, tj = blockIdx.x >> 2;
  int f = blockIdx.y, c = blockIdx.z;
  int i0 = ti * 128, j0 = tj * 128;
  int kbeg = c * CHK, kend = min(FOLD, kbeg + CHK);
  size_t basek = (size_t)f * FOLD;
  int t = threadIdx.x, lane = t & 63, w = t >> 6;
  int wm = (w & 1) * 64, wn = (w >> 1) * 64;
  floatx4 acc[4][4];
  #pragma unroll
  for (int a = 0; a < 4; ++a)
    #pragma unroll
    for (int b = 0; b < 4; ++b) acc[a][b] = (floatx4)0.f;
  for (int ks = kbeg; ks < kend; ks += 64) {
    #pragma unroll
    for (int q = 0; q < 4; ++q) {
      int lin = t + q * 256;
      int row = lin >> 3, col8 = (lin & 7) * 8;
      int gk = ks + col8;
      uint4 va = make_uint4(0, 0, 0, 0), vb = va;
      if (gk < kend) {
        va = *(const uint4*)(XT + (size_t)(i0 + row) * NROWS + basek + gk);
        vb = *(const uint4*)(XT + (size_t)(j0 + row) * NROWS + basek + gk);
      }
      *(uint4*)&Ab[row][col8] = va;
      *(uint4*)&Bb[row][col8] = vb;
    }
    __syncthreads();
    mfma_step(Ab, Bb, wm, wn, lane, acc);
    __syncthreads();
  }
  float* out = xxT + (size_t)f * DIM * DIM;
  #pragma unroll
  for (int mt = 0; mt < 4; ++mt)
    #pragma unroll
    for (int nt = 0; nt < 4; ++nt)
      #pragma unroll
      for (int i = 0; i < 4; ++i) {
        int row = i0 + wm + mt * 16 + ((lane >> 4) * 4 + i);
        int col = j0 + wn + nt * 16 + (lane & 15);
        atomicAdd(&out[row * DIM + col], acc[mt][nt][i]);
      }
}

// ---------- per-fold cross Gram (Y^T X), output [k][o][d] ----------
__global__ __launch_bounds__(256, 2) void k_gram_xy(const unsigned short* __restrict__ XT,
                                                    const float* __restrict__ Y,
                                                    float* __restrict__ xyT) {
  __shared__ unsigned short Ab[128][72];   // [o][n]
  __shared__ unsigned short Bb[128][72];   // [d][n]
  int ti = blockIdx.x & 1, tj = blockIdx.x >> 1;
  int f = blockIdx.y, c = blockIdx.z;
  int i0 = ti * 128, j0 = tj * 128;
  int kbeg = c * CHK, kend = min(FOLD, kbeg + CHK);
  int basek = f * FOLD;
  int t = threadIdx.x, lane = t & 63, w = t >> 6;
  int wm = (w & 1) * 64, wn = (w >> 1) * 64;
  floatx4 acc[4][4];
  #pragma unroll
  for (int a = 0; a < 4; ++a)
    #pragma unroll
    for (int b = 0; b < 4; ++b) acc[a][b] = (floatx4)0.f;
  for (int ks = kbeg; ks < kend; ks += 64) {
    #pragma unroll
    for (int q = 0; q < 8; ++q) {                       // stage Y -> transposed bf16
      int lin = t + q * 256;
      int nr = lin >> 5, c4 = (lin & 31) * 4;
      int gk = ks + nr;
      float4 v = make_float4(0.f, 0.f, 0.f, 0.f);
      if (gk < kend) v = *(const float4*)(Y + (size_t)(basek + gk) * ODIM + i0 + c4);
      Ab[c4 + 0][nr] = f2bf(v.x);
      Ab[c4 + 1][nr] = f2bf(v.y);
      Ab[c4 + 2][nr] = f2bf(v.z);
      Ab[c4 + 3][nr] = f2bf(v.w);
    }
    #pragma unroll
    for (int q = 0; q < 4; ++q) {                       // stage XT rows (d)
      int lin = t + q * 256;
      int row = lin >> 3, col8 = (lin & 7) * 8;
      int gk = ks + col8;
      uint4 vb = make_uint4(0, 0, 0, 0);
      if (gk < kend) vb = *(const uint4*)(XT + (size_t)(j0 + row) * NROWS + basek + gk);
      *(uint4*)&Bb[row][col8] = vb;
    }
    __syncthreads();
    mfma_step(Ab, Bb, wm, wn, lane, acc);
    __syncthreads();
  }
  float* out = xyT + (size_t)f * ODIM * DIM;
  #pragma unroll
  for (int mt = 0; mt < 4; ++mt)
    #pragma unroll
    for (int nt = 0; nt < 4; ++nt)
      #pragma unroll
      for (int i = 0; i < 4; ++i) {
        int row = i0 + wm + mt * 16 + ((lane >> 4) * 4 + i);
        int col = j0 + wn + nt * 16 + (lane & 15);
        atomicAdd(&out[row * DIM + col], acc[mt][nt][i]);
      }
}

// ---------- train means (5 LOO + full) ----------
__global__ void k_means(const float* __restrict__ sumX_f, const float* __restrict__ sumY_f,
                        float* __restrict__ muX, float* __restrict__ muY) {
  int g = blockIdx.x * 256 + threadIdx.x;
  if (g < 6 * DIM) {
    int k = g / DIM, d = g % DIM;
    float s = 0.f;
    #pragma unroll
    for (int kk = 0; kk < 5; ++kk) s += sumX_f[kk * DIM + d];
    muX[g] = (k < 5) ? (s - sumX_f[k * DIM + d]) / (float)NTR : s / (float)NROWS;
  } else {
    int g2 = g - 6 * DIM;
    int k = g2 / ODIM, o = g2 % ODIM;
    float s = 0.f;
    #pragma unroll
    for (int kk = 0; kk < 5; ++kk) s += sumY_f[kk * ODIM + o];
    muY[g2] = (k < 5) ? (s - sumY_f[k * ODIM + o]) / (float)NTR : s / (float)NROWS;
  }
}

// ---------- assemble A_k (LOO centered Gram, bf16) + Gv (val Gram, bf16) ----------
__global__ void k_asmA(const float* __restrict__ xxT, const float* __restrict__ muX,
                       unsigned short* __restrict__ Abf, unsigned short* __restrict__ Gv) {
  size_t g = (size_t)blockIdx.x * 256 + threadIdx.x;     // < 6*512*512
  int k = (int)(g / (DIM * DIM));
  int r = (int)(g % (DIM * DIM));
  int d = r / DIM, e = r % DIM;
  float s = 0.f;
  #pragma unroll
  for (int kk = 0; kk < 5; ++kk) s += xxT[(size_t)kk * DIM * DIM + r];
  float v;
  if (k < 5) {
    float own = xxT[(size_t)k * DIM * DIM + r];
    v = s - own - (float)NTR * muX[k * DIM + d] * muX[k * DIM + e];
    Gv[(size_t)k * DIM * DIM + r] = f2bf(own);
  } else {
    v = s - (float)NROWS * muX[5 * DIM + d] * muX[5 * DIM + e];
  }
  Abf[g] = f2bf(v);
}

// ---------- assemble B_k^T [k][o][d] f32 and init x0 for all 30 systems ----------
__global__ void k_asmB(const float* __restrict__ xyT, const float* __restrict__ muX,
                       const float* __restrict__ muY, float* __restrict__ BT,
                       unsigned short* __restrict__ x0) {
  int g = blockIdx.x * 256 + threadIdx.x;                // < 6*256*512
  int k = g / (ODIM * DIM);
  int r = g % (ODIM * DIM);
  int o = r / DIM, d = r % DIM;
  float s = 0.f;
  #pragma unroll
  for (int kk = 0; kk < 5; ++kk) s += xyT[(size_t)kk * ODIM * DIM + r];
  float v;
  if (k < 5) v = s - xyT[(size_t)k * ODIM * DIM + r] - (float)NTR * muY[k * ODIM + o] * muX[k * DIM + d];
  else       v = s - (float)NROWS * muY[5 * ODIM + o] * muX[5 * DIM + d];
  BT[g] = v;
  float halfsum = (k < 5) ? 40750.f : 50750.f;           // (a+b)/2 spectral midpoint
  #pragma unroll
  for (int l = 0; l < 5; ++l) {
    float th = halfsum + c_lam[l];
    x0[(size_t)(l * 6 + k) * (ODIM * DIM) + r] = f2bf(v / th);
  }
}

// ---------- one Richardson sweep over all 30 systems ----------
__global__ __launch_bounds__(256, 2) void k_rich(const unsigned short* __restrict__ xin,
                                                 unsigned short* __restrict__ xout,
                                                 const unsigned short* __restrict__ Abf,
                                                 const float* __restrict__ BT) {
  __shared__ unsigned short Xb[128][72];
  __shared__ unsigned short Mb[128][72];
  int tile = blockIdx.x;
  int o0 = (tile & 1) * 128, d0 = (tile >> 1) * 128;
  int s = blockIdx.y;
  int k = s % 6, l = s / 6;
  float lam = c_lam[l];
  float absum = (k < 5) ? 81500.f : 101500.f;
  float alpha = 2.f / (absum + 2.f * lam);
  const unsigned short* xs = xin + (size_t)s * ODIM * DIM;
  const unsigned short* Am = Abf + (size_t)k * DIM * DIM;
  int t = threadIdx.x, lane = t & 63, w = t >> 6;
  int wm = (w & 1) * 64, wn = (w >> 1) * 64;
  floatx4 acc[4][4];
  #pragma unroll
  for (int a = 0; a < 4; ++a)
    #pragma unroll
    for (int b = 0; b < 4; ++b) acc[a][b] = (floatx4)0.f;
  for (int ks = 0; ks < DIM; ks += 64) {
    #pragma unroll
    for (int q = 0; q < 4; ++q) {
      int lin = t + q * 256;
      int row = lin >> 3, col8 = (lin & 7) * 8;
      *(uint4*)&Xb[row][col8] = *(const uint4*)(xs + (size_t)(o0 + row) * DIM + ks + col8);
      *(uint4*)&Mb[row][col8] = *(const uint4*)(Am + (size_t)(d0 + row) * DIM + ks + col8);
    }
    __syncthreads();
    mfma_step(Xb, Mb, wm, wn, lane, acc);
    __syncthreads();
  }
  const float* Bk = BT + (size_t)k * ODIM * DIM;
  unsigned short* xo = xout + (size_t)s * ODIM * DIM;
  #pragma unroll
  for (int mt = 0; mt < 4; ++mt)
    #pragma unroll
    for (int nt = 0; nt < 4; ++nt)
      #pragma unroll
      for (int i = 0; i < 4; ++i) {
        int ro = o0 + wm + mt * 16 + ((lane >> 4) * 4 + i);
        int cd = d0 + wn + nt * 16 + (lane & 15);
        int idx = ro * DIM + cd;
        float xold = bf2f(xs[idx]);
        float r = Bk[idx] - acc[mt][nt][i] - lam * xold;
        xo[idx] = f2bf(xold + alpha * r);
      }
}

// ---------- tr(W^T Gv W) via GEMM + dot, atomic per (l,k) ----------
__global__ __launch_bounds__(256, 2) void k_loss_big(const unsigned short* __restrict__ x,
                                                     const unsigned short* __restrict__ Gv,
                                                     float* __restrict__ SSEb) {
  __shared__ unsigned short Xb[128][72];
  __shared__ unsigned short Mb[128][72];
  int tile = blockIdx.x;
  int o0 = (tile & 1) * 128, d0 = (tile >> 1) * 128;
  int s25 = blockIdx.y;
  int k = s25 % 5, l = s25 / 5;
  int s = l * 6 + k;
  const unsigned short* xs = x + (size_t)s * ODIM * DIM;
  const unsigned short* Gm = Gv + (size_t)k * DIM * DIM;
  int t = threadIdx.x, lane = t & 63, w = t >> 6;
  int wm = (w & 1) * 64, wn = (w >> 1) * 64;
  floatx4 acc[4][4];
  #pragma unroll
  for (int a = 0; a < 4; ++a)
    #pragma unroll
    for (int b = 0; b < 4; ++b) acc[a][b] = (floatx4)0.f;
  for (int ks = 0; ks < DIM; ks += 64) {
    #pragma unroll
    for (int q = 0; q < 4; ++q) {
      int lin = t + q * 256;
      int row = lin >> 3, col8 = (lin & 7) * 8;
      *(uint4*)&Xb[row][col8] = *(const uint4*)(xs + (size_t)(o0 + row) * DIM + ks + col8);
      *(uint4*)&Mb[row][col8] = *(const uint4*)(Gm + (size_t)(d0 + row) * DIM + ks + col8);
    }
    __syncthreads();
    mfma_step(Xb, Mb, wm, wn, lane, acc);
    __syncthreads();
  }
  float part = 0.f;
  #pragma unroll
  for (int mt = 0; mt < 4; ++mt)
    #pragma unroll
    for (int nt = 0; nt < 4; ++nt)
      #pragma unroll
      for (int i = 0; i < 4; ++i) {
        int ro = o0 + wm + mt * 16 + ((lane >> 4) * 4 + i);
        int cd = d0 + wn + nt * 16 + (lane & 15);
        part += acc[mt][nt][i] * bf2f(xs[ro * DIM + cd]);
      }
  float tot = block_sum256(part);
  if (threadIdx.x == 0) atomicAdd(&SSEb[s25], tot);
}

// ---------- linear/const SSE terms per (l,k) ----------
__global__ __launch_bounds__(256) void k_loss_small(const unsigned short* __restrict__ x,
                                                    const float* __restrict__ xyT,
                                                    const float* __restrict__ muX,
                                                    const float* __restrict__ muY,
                                                    const float* __restrict__ sumX_f,
                                                    const float* __restrict__ sumY_f,
                                                    const float* __restrict__ yy_f,
                                                    float* __restrict__ SSEs) {
  __shared__ float lmu[DIM];
  __shared__ float lsx[DIM];
  int s25 = blockIdx.x;
  int k = s25 % 5, l = s25 / 5;
  int sidx = l * 6 + k;
  int o = threadIdx.x;
  lmu[o] = muX[k * DIM + o];       lmu[o + 256] = muX[k * DIM + o + 256];
  lsx[o] = sumX_f[k * DIM + o];    lsx[o + 256] = sumX_f[k * DIM + o + 256];
  __syncthreads();
  const unsigned short* xr = x + (size_t)sidx * ODIM * DIM + (size_t)o * DIM;
  const float* cv = xyT + (size_t)k * ODIM * DIM + (size_t)o * DIM;
  float t1 = 0.f, t2 = 0.f, trc = 0.f;
  for (int d = 0; d < DIM; d += 4) {
    ushort4 xv = *(const ushort4*)(xr + d);
    float4 cf = *(const float4*)(cv + d);
    float a0 = bf2f(xv.x), a1 = bf2f(xv.y), a2 = bf2f(xv.z), a3 = bf2f(xv.w);
    t1 += a0 * lsx[d] + a1 * lsx[d + 1] + a2 * lsx[d + 2] + a3 * lsx[d + 3];
    t2 += a0 * lmu[d] + a1 * lmu[d + 1] + a2 * lmu[d + 2] + a3 * lmu[d + 3];
    trc += a0 * cf.x + a1 * cf.y + a2 * cf.z + a3 * cf.w;
  }
  float b = muY[k * ODIM + o] - t2;
  float syv = sumY_f[k * ODIM + o];
  float part = 2.f * b * t1 + (float)FOLD * b * b - 2.f * trc - 2.f * b * syv;
  float tot = block_sum256(part);
  if (threadIdx.x == 0) SSEs[s25] = tot + yy_f[k];
}

// ---------- losses + argmin ----------
__global__ void k_loss_final(const float* __restrict__ SSEs, const float* __restrict__ SSEb,
                             float* __restrict__ out, int* __restrict__ aidx) {
  if (threadIdx.x == 0) {
    float best = 1e30f; int bi = 0;
    for (int l = 0; l < 5; ++l) {
      float s = 0.f;
      for (int k = 0; k < 5; ++k) s += SSEs[l * 5 + k] + SSEb[l * 5 + k];
      float loss = s / (float)(FOLDS * FOLD * ODIM);
      out[131072 + 256 + l] = loss;
      if (loss < best) { best = loss; bi = l; }
    }
    aidx[0] = bi;
  }
}

// ---------- outputs ----------
__global__ void k_outW(const unsigned short* __restrict__ x, const int* __restrict__ aidx,
                       float* __restrict__ out) {
  int g = blockIdx.x * 256 + threadIdx.x;
  int s = aidx[0] * 6 + 5;
  out[g] = bf2f(x[(size_t)s * ODIM * DIM + g]);
}

__global__ __launch_bounds__(64) void k_outB(const unsigned short* __restrict__ x,
                                             const float* __restrict__ muX,
                                             const float* __restrict__ muY,
                                             const int* __restrict__ aidx,
                                             float* __restrict__ out) {
  int o = blockIdx.x, lane = threadIdx.x;
  int s = aidx[0] * 6 + 5;
  const unsigned short* xr = x + (size_t)s * ODIM * DIM + (size_t)o * DIM;
  float dsum = 0.f;
  for (int d = lane; d < DIM; d += 64) dsum += bf2f(xr[d]) * muX[5 * DIM + d];
  for (int off = 32; off; off >>= 1) dsum += __shfl_down(dsum, off, 64);
  if (lane == 0) out[131072 + o] = muY[5 * ODIM + o] - dsum;
}

extern "C" void kernel_launch(void* const* d_in, const int* in_sizes, int n_in,
                              void* d_out, int out_size, void* d_ws, size_t ws_size,
                              hipStream_t stream) {
  const float* X = (const float*)d_in[0];
  const float* Y = (const float*)d_in[1];
  float* out = (float*)d_out;
  char* ws = (char*)d_ws;
  size_t off = 0;
  auto alloc = [&](size_t bytes) {
    size_t cur = off;
    off = (off + bytes + 255) & ~(size_t)255;
    return cur;
  };
  unsigned short* XT = (unsigned short*)(ws + alloc((size_t)DIM * NROWS * 2));
  size_t zbeg = off;
  float* xxT    = (float*)(ws + alloc((size_t)5 * DIM * DIM * 4));
  float* xyT    = (float*)(ws + alloc((size_t)5 * ODIM * DIM * 4));
  float* sumY_f = (float*)(ws + alloc(5 * ODIM * 4));
  float* yy_f   = (float*)(ws + alloc(5 * 4));
  float* SSEb   = (float*)(ws + alloc(25 * 4));
  size_t zend = off;
  float* sumX_f = (float*)(ws + alloc(5 * DIM * 4));
  float* muX    = (float*)(ws + alloc(6 * DIM * 4));
  float* muY    = (float*)(ws + alloc(6 * ODIM * 4));
  unsigned short* Abf = (unsigned short*)(ws + alloc((size_t)6 * DIM * DIM * 2));
  unsigned short* Gv  = (unsigned short*)(ws + alloc((size_t)5 * DIM * DIM * 2));
  float* BT     = (float*)(ws + alloc((size_t)6 * ODIM * DIM * 4));
  unsigned short* x0 = (unsigned short*)(ws + alloc((size_t)30 * ODIM * DIM * 2));
  unsigned short* x1 = (unsigned short*)(ws + alloc((size_t)30 * ODIM * DIM * 2));
  float* SSEs   = (float*)(ws + alloc(25 * 4));
  int* aidx     = (int*)(ws + alloc(4));

  hipMemsetAsync(ws + zbeg, 0, zend - zbeg, stream);

  k_tX<<<dim3(782, 8), 256, 0, stream>>>(X, XT);
  k_sumX<<<5 * DIM, 64, 0, stream>>>(XT, sumX_f);
  k_sumY<<<dim3(5, 125), 256, 0, stream>>>(Y, sumY_f, yy_f);
  k_gram_xx<<<dim3(16, 5, NCHUNK), 256, 0, stream>>>(XT, xxT);
  k_gram_xy<<<dim3(8, 5, NCHUNK), 256, 0, stream>>>(XT, Y, xyT);
  k_means<<<18, 256, 0, stream>>>(sumX_f, sumY_f, muX, muY);
  k_asmA<<<6 * DIM * DIM / 256, 256, 0, stream>>>(xxT, muX, Abf, Gv);
  k_asmB<<<6 * ODIM * DIM / 256, 256, 0, stream>>>(xyT, muX, muY, BT, x0);
  for (int it = 0; it < 8; ++it) {
    const unsigned short* xin = (it & 1) ? x1 : x0;
    unsigned short* xout = (it & 1) ? x0 : x1;
    k_rich<<<dim3(8, 30), 256, 0, stream>>>(xin, xout, Abf, BT);
  }
  // after 8 iterations result is back in x0
  k_loss_small<<<25, 256, 0, stream>>>(x0, xyT, muX, muY, sumX_f, sumY_f, yy_f, SSEs);
  k_loss_big<<<dim3(8, 25), 256, 0, stream>>>(x0, Gv, SSEb);
  k_loss_final<<<1, 64, 0, stream>>>(SSEs, SSEb, out, aidx);
  k_outW<<<DIM * ODIM / 256 * 2 / 2, 256, 0, stream>>>(x0, aidx, out);  // 512 blocks
  k_outB<<<ODIM, 64, 0, stream>>>(x0, muX, muY, aidx, out);
}

// Round 5
// 516.113 us; speedup vs baseline: 1.6128x; 1.1542x over previous
//
#include <hip/hip_runtime.h>
#include <stdint.h>

#define NROWS 50000
#define DIM   512
#define ODIM  256
#define FOLDS 5
#define FOLD  10000
#define NTR   40000
#define CHKG  1000
#define NCHUNK 10

__constant__ float c_lam[5] = {0.01f, 0.1f, 1.0f, 10.0f, 100.0f};
// tile pairs for fused gram: 10 xx upper-triangle + 8 xy (A=Y rows 512+, B=X rows)
__constant__ int c_pA[18] = {0,0,0,0,128,128,128,256,256,384, 512,512,512,512,640,640,640,640};
__constant__ int c_pB[18] = {0,128,256,384,128,256,384,256,384,384, 0,128,256,384,0,128,256,384};

typedef __attribute__((ext_vector_type(8))) short short8;
typedef __attribute__((ext_vector_type(4))) float floatx4;

__device__ __forceinline__ unsigned short f2bf(float f) {
  unsigned u = __float_as_uint(f);
  u += 0x7FFFu + ((u >> 16) & 1u);          // RNE
  return (unsigned short)(u >> 16);
}
__device__ __forceinline__ float bf2f(unsigned short h) {
  return __uint_as_float(((unsigned)h) << 16);
}

__device__ __forceinline__ float block_sum256(float v) {
  __shared__ float red[4];
  for (int off = 32; off; off >>= 1) v += __shfl_down(v, off, 64);
  if ((threadIdx.x & 63) == 0) red[threadIdx.x >> 6] = v;
  __syncthreads();
  float r = 0.f;
  if (threadIdx.x == 0) r = red[0] + red[1] + red[2] + red[3];
  return r;
}

// ---------- transpose X [50000,512] f32 -> ZT rows [0,512) bf16 ----------
__global__ __launch_bounds__(256) void k_tX(const float* __restrict__ X,
                                            unsigned short* __restrict__ ZT) {
  __shared__ unsigned short lds[64][72];
  int n0 = blockIdx.x * 64, d0 = blockIdx.y * 64;
  int t = threadIdx.x;
  #pragma unroll
  for (int p = 0; p < 4; ++p) {
    int r = p * 16 + (t >> 4);
    int c = (t & 15) * 4;
    int n = n0 + r;
    float4 v = make_float4(0.f, 0.f, 0.f, 0.f);
    if (n < NROWS) v = *(const float4*)(X + (size_t)n * DIM + d0 + c);
    lds[c + 0][r] = f2bf(v.x);
    lds[c + 1][r] = f2bf(v.y);
    lds[c + 2][r] = f2bf(v.z);
    lds[c + 3][r] = f2bf(v.w);
  }
  __syncthreads();
  #pragma unroll
  for (int p = 0; p < 2; ++p) {
    int d = p * 32 + (t >> 3);
    int nc = (t & 7) * 8;
    if (n0 + nc < NROWS) {
      uint4 v = *(const uint4*)&lds[d][nc];
      *(uint4*)(ZT + (size_t)(d0 + d) * NROWS + n0 + nc) = v;
    }
  }
}

// ---------- transpose Y [50000,256] f32 -> ZT rows [512,768) bf16 ----------
__global__ __launch_bounds__(256) void k_tY(const float* __restrict__ Y,
                                            unsigned short* __restrict__ ZT) {
  __shared__ unsigned short lds[64][72];
  int n0 = blockIdx.x * 64, d0 = blockIdx.y * 64;
  int t = threadIdx.x;
  #pragma unroll
  for (int p = 0; p < 4; ++p) {
    int r = p * 16 + (t >> 4);
    int c = (t & 15) * 4;
    int n = n0 + r;
    float4 v = make_float4(0.f, 0.f, 0.f, 0.f);
    if (n < NROWS) v = *(const float4*)(Y + (size_t)n * ODIM + d0 + c);
    lds[c + 0][r] = f2bf(v.x);
    lds[c + 1][r] = f2bf(v.y);
    lds[c + 2][r] = f2bf(v.z);
    lds[c + 3][r] = f2bf(v.w);
  }
  __syncthreads();
  #pragma unroll
  for (int p = 0; p < 2; ++p) {
    int d = p * 32 + (t >> 3);
    int nc = (t & 7) * 8;
    if (n0 + nc < NROWS) {
      uint4 v = *(const uint4*)&lds[d][nc];
      *(uint4*)(ZT + (size_t)(512 + d0 + d) * NROWS + n0 + nc) = v;
    }
  }
}

// ---------- per-fold column sums of X (from ZT rows 0..511) ----------
__global__ __launch_bounds__(64) void k_sumX(const unsigned short* __restrict__ ZT,
                                             float* __restrict__ sumX_f) {
  int seg = blockIdx.x;            // k*512 + d
  int k = seg / DIM, d = seg % DIM;
  const unsigned short* row = ZT + (size_t)d * NROWS + k * FOLD;
  float s = 0.f;
  for (int i = threadIdx.x * 4; i < FOLD; i += 64 * 4) {
    ushort4 v = *(const ushort4*)(row + i);
    s += bf2f(v.x) + bf2f(v.y) + bf2f(v.z) + bf2f(v.w);
  }
  for (int off = 32; off; off >>= 1) s += __shfl_down(s, off, 64);
  if (threadIdx.x == 0) sumX_f[seg] = s;
}

// ---------- per-fold sums of Y and sum of Y^2 ----------
__global__ __launch_bounds__(256) void k_sumY(const float* __restrict__ Y,
                                              float* __restrict__ sumY_f,
                                              float* __restrict__ yy_f) {
  __shared__ float sh[4][ODIM];
  int k = blockIdx.x, ch = blockIdx.y;
  int lane = threadIdx.x & 63, grp = threadIdx.x >> 6;
  int nbeg = k * FOLD + ch * 80;
  float s0 = 0.f, s1 = 0.f, s2 = 0.f, s3 = 0.f, q = 0.f;
  #pragma unroll 4
  for (int r = 0; r < 80; r += 4) {
    int n = nbeg + r + grp;
    float4 v = *(const float4*)(Y + (size_t)n * ODIM + lane * 4);
    s0 += v.x; s1 += v.y; s2 += v.z; s3 += v.w;
    q += v.x * v.x + v.y * v.y + v.z * v.z + v.w * v.w;
  }
  sh[grp][lane * 4 + 0] = s0;
  sh[grp][lane * 4 + 1] = s1;
  sh[grp][lane * 4 + 2] = s2;
  sh[grp][lane * 4 + 3] = s3;
  __syncthreads();
  int o = threadIdx.x;
  float t = sh[0][o] + sh[1][o] + sh[2][o] + sh[3][o];
  atomicAdd(&sumY_f[k * ODIM + o], t);
  float qt = block_sum256(q);
  if (threadIdx.x == 0) atomicAdd(&yy_f[k], qt);
}

// ---------- MFMA inner step: D += A*B over K=64 staged in LDS ----------
__device__ __forceinline__ void mfma_step(const unsigned short (*A)[72],
                                          const unsigned short (*B)[72],
                                          int wm, int wn, int lane,
                                          floatx4 acc[4][4]) {
  int fr = lane & 15;
  int fq = (lane >> 4) * 8;
  #pragma unroll
  for (int kk = 0; kk < 64; kk += 32) {
    short8 af[4], bfv[4];
    #pragma unroll
    for (int mt = 0; mt < 4; ++mt)
      af[mt] = *(const short8*)&A[wm + mt * 16 + fr][kk + fq];
    #pragma unroll
    for (int nt = 0; nt < 4; ++nt)
      bfv[nt] = *(const short8*)&B[wn + nt * 16 + fr][kk + fq];
    #pragma unroll
    for (int mt = 0; mt < 4; ++mt)
      #pragma unroll
      for (int nt = 0; nt < 4; ++nt)
        acc[mt][nt] = __builtin_amdgcn_mfma_f32_16x16x32_bf16(af[mt], bfv[nt], acc[mt][nt], 0, 0, 0);
  }
}

// ---------- fused per-fold Gram over ZT=[XT;YT]: xx upper-tri + Y^T X ----------
__global__ __launch_bounds__(256, 2) void k_gram(const unsigned short* __restrict__ ZT,
                                                 float* __restrict__ xxT,
                                                 float* __restrict__ xyT) {
  __shared__ unsigned short Ab[128][72];
  __shared__ unsigned short Bb[128][72];
  int p = blockIdx.x, f = blockIdx.y, c = blockIdx.z;
  int i0 = c_pA[p], j0 = c_pB[p];
  int kbeg = c * CHKG, kend = kbeg + CHKG;
  size_t basek = (size_t)f * FOLD;
  int t = threadIdx.x, lane = t & 63, w = t >> 6;
  int wm = (w & 1) * 64, wn = (w >> 1) * 64;
  floatx4 acc[4][4];
  #pragma unroll
  for (int a = 0; a < 4; ++a)
    #pragma unroll
    for (int b = 0; b < 4; ++b) acc[a][b] = (floatx4)0.f;
  for (int ks = kbeg; ks < kend; ks += 64) {
    #pragma unroll
    for (int q = 0; q < 4; ++q) {
      int lin = t + q * 256;
      int row = lin >> 3, col8 = (lin & 7) * 8;
      int gk = ks + col8;
      uint4 va = make_uint4(0, 0, 0, 0), vb = va;
      if (gk < kend) {
        va = *(const uint4*)(ZT + (size_t)(i0 + row) * NROWS + basek + gk);
        vb = *(const uint4*)(ZT + (size_t)(j0 + row) * NROWS + basek + gk);
      }
      *(uint4*)&Ab[row][col8] = va;
      *(uint4*)&Bb[row][col8] = vb;
    }
    __syncthreads();
    mfma_step(Ab, Bb, wm, wn, lane, acc);
    __syncthreads();
  }
  #pragma unroll
  for (int mt = 0; mt < 4; ++mt)
    #pragma unroll
    for (int nt = 0; nt < 4; ++nt)
      #pragma unroll
      for (int i = 0; i < 4; ++i) {
        int rr = wm + mt * 16 + ((lane >> 4) * 4 + i);
        int cc = wn + nt * 16 + (lane & 15);
        if (p < 10)
          atomicAdd(&xxT[(size_t)f * DIM * DIM + (i0 + rr) * DIM + (j0 + cc)], acc[mt][nt][i]);
        else
          atomicAdd(&xyT[(size_t)f * ODIM * DIM + (i0 - 512 + rr) * DIM + (j0 + cc)], acc[mt][nt][i]);
      }
}

// ---------- train means (5 LOO + full) ----------
__global__ void k_means(const float* __restrict__ sumX_f, const float* __restrict__ sumY_f,
                        float* __restrict__ muX, float* __restrict__ muY) {
  int g = blockIdx.x * 256 + threadIdx.x;
  if (g < 6 * DIM) {
    int k = g / DIM, d = g % DIM;
    float s = 0.f;
    #pragma unroll
    for (int kk = 0; kk < 5; ++kk) s += sumX_f[kk * DIM + d];
    muX[g] = (k < 5) ? (s - sumX_f[k * DIM + d]) / (float)NTR : s / (float)NROWS;
  } else {
    int g2 = g - 6 * DIM;
    int k = g2 / ODIM, o = g2 % ODIM;
    float s = 0.f;
    #pragma unroll
    for (int kk = 0; kk < 5; ++kk) s += sumY_f[kk * ODIM + o];
    muY[g2] = (k < 5) ? (s - sumY_f[k * ODIM + o]) / (float)NTR : s / (float)NROWS;
  }
}

// ---------- assemble A_k (bf16) + Gv (bf16); xxT stored upper-tri, mirror on read ----------
__global__ void k_asmA(const float* __restrict__ xxT, const float* __restrict__ muX,
                       unsigned short* __restrict__ Abf, unsigned short* __restrict__ Gv) {
  size_t g = (size_t)blockIdx.x * 256 + threadIdx.x;     // < 6*512*512
  int k = (int)(g / (DIM * DIM));
  int r = (int)(g % (DIM * DIM));
  int d = r / DIM, e = r % DIM;
  int ridx = (d <= e) ? r : (e * DIM + d);
  float s = 0.f;
  #pragma unroll
  for (int kk = 0; kk < 5; ++kk) s += xxT[(size_t)kk * DIM * DIM + ridx];
  float v;
  if (k < 5) {
    float own = xxT[(size_t)k * DIM * DIM + ridx];
    v = s - own - (float)NTR * muX[k * DIM + d] * muX[k * DIM + e];
    Gv[(size_t)k * DIM * DIM + r] = f2bf(own);
  } else {
    v = s - (float)NROWS * muX[5 * DIM + d] * muX[5 * DIM + e];
  }
  Abf[g] = f2bf(v);
}

// ---------- assemble B_k^T [k][o][d] f32 and init x0 for all 30 systems ----------
__global__ void k_asmB(const float* __restrict__ xyT, const float* __restrict__ muX,
                       const float* __restrict__ muY, float* __restrict__ BT,
                       unsigned short* __restrict__ x0) {
  int g = blockIdx.x * 256 + threadIdx.x;                // < 6*256*512
  int k = g / (ODIM * DIM);
  int r = g % (ODIM * DIM);
  int o = r / DIM, d = r % DIM;
  float s = 0.f;
  #pragma unroll
  for (int kk = 0; kk < 5; ++kk) s += xyT[(size_t)kk * ODIM * DIM + r];
  float v;
  if (k < 5) v = s - xyT[(size_t)k * ODIM * DIM + r] - (float)NTR * muY[k * ODIM + o] * muX[k * DIM + d];
  else       v = s - (float)NROWS * muY[5 * ODIM + o] * muX[5 * DIM + d];
  BT[g] = v;
  float halfsum = (k < 5) ? 40750.f : 50750.f;           // (a+b)/2 spectral midpoint
  #pragma unroll
  for (int l = 0; l < 5; ++l) {
    float th = halfsum + c_lam[l];
    x0[(size_t)(l * 6 + k) * (ODIM * DIM) + r] = f2bf(v / th);
  }
}

// ---------- one Richardson sweep; k5only=1 restricts to the 5 full-data systems ----------
__global__ __launch_bounds__(256, 2) void k_rich(const unsigned short* __restrict__ xin,
                                                 unsigned short* __restrict__ xout,
                                                 const unsigned short* __restrict__ Abf,
                                                 const float* __restrict__ BT,
                                                 int k5only) {
  __shared__ unsigned short Xb[128][72];
  __shared__ unsigned short Mb[128][72];
  int tile = blockIdx.x;
  int o0 = (tile & 1) * 128, d0 = (tile >> 1) * 128;
  int s = k5only ? (blockIdx.y * 6 + 5) : blockIdx.y;
  int k = s % 6, l = s / 6;
  float lam = c_lam[l];
  float absum = (k < 5) ? 81500.f : 101500.f;
  float alpha = 2.f / (absum + 2.f * lam);
  const unsigned short* xs = xin + (size_t)s * ODIM * DIM;
  const unsigned short* Am = Abf + (size_t)k * DIM * DIM;
  int t = threadIdx.x, lane = t & 63, w = t >> 6;
  int wm = (w & 1) * 64, wn = (w >> 1) * 64;
  floatx4 acc[4][4];
  #pragma unroll
  for (int a = 0; a < 4; ++a)
    #pragma unroll
    for (int b = 0; b < 4; ++b) acc[a][b] = (floatx4)0.f;
  for (int ks = 0; ks < DIM; ks += 64) {
    #pragma unroll
    for (int q = 0; q < 4; ++q) {
      int lin = t + q * 256;
      int row = lin >> 3, col8 = (lin & 7) * 8;
      *(uint4*)&Xb[row][col8] = *(const uint4*)(xs + (size_t)(o0 + row) * DIM + ks + col8);
      *(uint4*)&Mb[row][col8] = *(const uint4*)(Am + (size_t)(d0 + row) * DIM + ks + col8);
    }
    __syncthreads();
    mfma_step(Xb, Mb, wm, wn, lane, acc);
    __syncthreads();
  }
  const float* Bk = BT + (size_t)k * ODIM * DIM;
  unsigned short* xo = xout + (size_t)s * ODIM * DIM;
  #pragma unroll
  for (int mt = 0; mt < 4; ++mt)
    #pragma unroll
    for (int nt = 0; nt < 4; ++nt)
      #pragma unroll
      for (int i = 0; i < 4; ++i) {
        int ro = o0 + wm + mt * 16 + ((lane >> 4) * 4 + i);
        int cd = d0 + wn + nt * 16 + (lane & 15);
        int idx = ro * DIM + cd;
        float xold = bf2f(xs[idx]);
        float r = Bk[idx] - acc[mt][nt][i] - lam * xold;
        xo[idx] = f2bf(xold + alpha * r);
      }
}

// ---------- tr(W^T Gv W) via GEMM + dot, atomic per (l,k) ----------
__global__ __launch_bounds__(256, 2) void k_loss_big(const unsigned short* __restrict__ x,
                                                     const unsigned short* __restrict__ Gv,
                                                     float* __restrict__ SSEb) {
  __shared__ unsigned short Xb[128][72];
  __shared__ unsigned short Mb[128][72];
  int tile = blockIdx.x;
  int o0 = (tile & 1) * 128, d0 = (tile >> 1) * 128;
  int s25 = blockIdx.y;
  int k = s25 % 5, l = s25 / 5;
  int s = l * 6 + k;
  const unsigned short* xs = x + (size_t)s * ODIM * DIM;
  const unsigned short* Gm = Gv + (size_t)k * DIM * DIM;
  int t = threadIdx.x, lane = t & 63, w = t >> 6;
  int wm = (w & 1) * 64, wn = (w >> 1) * 64;
  floatx4 acc[4][4];
  #pragma unroll
  for (int a = 0; a < 4; ++a)
    #pragma unroll
    for (int b = 0; b < 4; ++b) acc[a][b] = (floatx4)0.f;
  for (int ks = 0; ks < DIM; ks += 64) {
    #pragma unroll
    for (int q = 0; q < 4; ++q) {
      int lin = t + q * 256;
      int row = lin >> 3, col8 = (lin & 7) * 8;
      *(uint4*)&Xb[row][col8] = *(const uint4*)(xs + (size_t)(o0 + row) * DIM + ks + col8);
      *(uint4*)&Mb[row][col8] = *(const uint4*)(Gm + (size_t)(d0 + row) * DIM + ks + col8);
    }
    __syncthreads();
    mfma_step(Xb, Mb, wm, wn, lane, acc);
    __syncthreads();
  }
  float part = 0.f;
  #pragma unroll
  for (int mt = 0; mt < 4; ++mt)
    #pragma unroll
    for (int nt = 0; nt < 4; ++nt)
      #pragma unroll
      for (int i = 0; i < 4; ++i) {
        int ro = o0 + wm + mt * 16 + ((lane >> 4) * 4 + i);
        int cd = d0 + wn + nt * 16 + (lane & 15);
        part += acc[mt][nt][i] * bf2f(xs[ro * DIM + cd]);
      }
  float tot = block_sum256(part);
  if (threadIdx.x == 0) atomicAdd(&SSEb[s25], tot);
}

// ---------- linear/const SSE terms per (l,k) ----------
__global__ __launch_bounds__(256) void k_loss_small(const unsigned short* __restrict__ x,
                                                    const float* __restrict__ xyT,
                                                    const float* __restrict__ muX,
                                                    const float* __restrict__ muY,
                                                    const float* __restrict__ sumX_f,
                                                    const float* __restrict__ sumY_f,
                                                    const float* __restrict__ yy_f,
                                                    float* __restrict__ SSEs) {
  __shared__ float lmu[DIM];
  __shared__ float lsx[DIM];
  int s25 = blockIdx.x;
  int k = s25 % 5, l = s25 / 5;
  int sidx = l * 6 + k;
  int o = threadIdx.x;
  lmu[o] = muX[k * DIM + o];       lmu[o + 256] = muX[k * DIM + o + 256];
  lsx[o] = sumX_f[k * DIM + o];    lsx[o + 256] = sumX_f[k * DIM + o + 256];
  __syncthreads();
  const unsigned short* xr = x + (size_t)sidx * ODIM * DIM + (size_t)o * DIM;
  const float* cv = xyT + (size_t)k * ODIM * DIM + (size_t)o * DIM;
  float t1 = 0.f, t2 = 0.f, trc = 0.f;
  for (int d = 0; d < DIM; d += 4) {
    ushort4 xv = *(const ushort4*)(xr + d);
    float4 cf = *(const float4*)(cv + d);
    float a0 = bf2f(xv.x), a1 = bf2f(xv.y), a2 = bf2f(xv.z), a3 = bf2f(xv.w);
    t1 += a0 * lsx[d] + a1 * lsx[d + 1] + a2 * lsx[d + 2] + a3 * lsx[d + 3];
    t2 += a0 * lmu[d] + a1 * lmu[d + 1] + a2 * lmu[d + 2] + a3 * lmu[d + 3];
    trc += a0 * cf.x + a1 * cf.y + a2 * cf.z + a3 * cf.w;
  }
  float b = muY[k * ODIM + o] - t2;
  float syv = sumY_f[k * ODIM + o];
  float part = 2.f * b * t1 + (float)FOLD * b * b - 2.f * trc - 2.f * b * syv;
  float tot = block_sum256(part);
  if (threadIdx.x == 0) SSEs[s25] = tot + yy_f[k];
}

// ---------- losses + argmin ----------
__global__ void k_loss_final(const float* __restrict__ SSEs, const float* __restrict__ SSEb,
                             float* __restrict__ out, int* __restrict__ aidx) {
  if (threadIdx.x == 0) {
    float best = 1e30f; int bi = 0;
    for (int l = 0; l < 5; ++l) {
      float s = 0.f;
      for (int k = 0; k < 5; ++k) s += SSEs[l * 5 + k] + SSEb[l * 5 + k];
      float loss = s / (float)(FOLDS * FOLD * ODIM);
      out[131072 + 256 + l] = loss;
      if (loss < best) { best = loss; bi = l; }
    }
    aidx[0] = bi;
  }
}

// ---------- outputs ----------
__global__ void k_outW(const unsigned short* __restrict__ x, const int* __restrict__ aidx,
                       float* __restrict__ out) {
  int g = blockIdx.x * 256 + threadIdx.x;
  int s = aidx[0] * 6 + 5;
  out[g] = bf2f(x[(size_t)s * ODIM * DIM + g]);
}

__global__ __launch_bounds__(64) void k_outB(const unsigned short* __restrict__ x,
                                             const float* __restrict__ muX,
                                             const float* __restrict__ muY,
                                             const int* __restrict__ aidx,
                                             float* __restrict__ out) {
  int o = blockIdx.x, lane = threadIdx.x;
  int s = aidx[0] * 6 + 5;
  const unsigned short* xr = x + (size_t)s * ODIM * DIM + (size_t)o * DIM;
  float dsum = 0.f;
  for (int d = lane; d < DIM; d += 64) dsum += bf2f(xr[d]) * muX[5 * DIM + d];
  for (int off = 32; off; off >>= 1) dsum += __shfl_down(dsum, off, 64);
  if (lane == 0) out[131072 + o] = muY[5 * ODIM + o] - dsum;
}

extern "C" void kernel_launch(void* const* d_in, const int* in_sizes, int n_in,
                              void* d_out, int out_size, void* d_ws, size_t ws_size,
                              hipStream_t stream) {
  const float* X = (const float*)d_in[0];
  const float* Y = (const float*)d_in[1];
  float* out = (float*)d_out;
  char* ws = (char*)d_ws;
  size_t off = 0;
  auto alloc = [&](size_t bytes) {
    size_t cur = off;
    off = (off + bytes + 255) & ~(size_t)255;
    return cur;
  };
  unsigned short* ZT = (unsigned short*)(ws + alloc((size_t)768 * NROWS * 2));
  size_t zbeg = off;
  float* xxT    = (float*)(ws + alloc((size_t)5 * DIM * DIM * 4));
  float* xyT    = (float*)(ws + alloc((size_t)5 * ODIM * DIM * 4));
  float* sumY_f = (float*)(ws + alloc(5 * ODIM * 4));
  float* yy_f   = (float*)(ws + alloc(5 * 4));
  float* SSEb   = (float*)(ws + alloc(25 * 4));
  size_t zend = off;
  float* sumX_f = (float*)(ws + alloc(5 * DIM * 4));
  float* muX    = (float*)(ws + alloc(6 * DIM * 4));
  float* muY    = (float*)(ws + alloc(6 * ODIM * 4));
  unsigned short* Abf = (unsigned short*)(ws + alloc((size_t)6 * DIM * DIM * 2));
  unsigned short* Gv  = (unsigned short*)(ws + alloc((size_t)5 * DIM * DIM * 2));
  float* BT     = (float*)(ws + alloc((size_t)6 * ODIM * DIM * 4));
  unsigned short* x0 = (unsigned short*)(ws + alloc((size_t)30 * ODIM * DIM * 2));
  unsigned short* x1 = (unsigned short*)(ws + alloc((size_t)30 * ODIM * DIM * 2));
  float* SSEs   = (float*)(ws + alloc(25 * 4));
  int* aidx     = (int*)(ws + alloc(4));

  hipMemsetAsync(ws + zbeg, 0, zend - zbeg, stream);

  k_tX<<<dim3(782, 8), 256, 0, stream>>>(X, ZT);
  k_tY<<<dim3(782, 4), 256, 0, stream>>>(Y, ZT);
  k_sumX<<<5 * DIM, 64, 0, stream>>>(ZT, sumX_f);
  k_sumY<<<dim3(5, 125), 256, 0, stream>>>(Y, sumY_f, yy_f);
  k_gram<<<dim3(18, 5, NCHUNK), 256, 0, stream>>>(ZT, xxT, xyT);
  k_means<<<18, 256, 0, stream>>>(sumX_f, sumY_f, muX, muY);
  k_asmA<<<6 * DIM * DIM / 256, 256, 0, stream>>>(xxT, muX, Abf, Gv);
  k_asmB<<<6 * ODIM * DIM / 256, 256, 0, stream>>>(xyT, muX, muY, BT, x0);
  // sweeps: 3 over all 30 systems, +1 over the 5 full-data (k=5) systems.
  // CV final state lands in x1; full-data final state lands in x0.
  k_rich<<<dim3(8, 30), 256, 0, stream>>>(x0, x1, Abf, BT, 0);
  k_rich<<<dim3(8, 30), 256, 0, stream>>>(x1, x0, Abf, BT, 0);
  k_rich<<<dim3(8, 30), 256, 0, stream>>>(x0, x1, Abf, BT, 0);
  k_rich<<<dim3(8, 5),  256, 0, stream>>>(x1, x0, Abf, BT, 1);
  k_loss_small<<<25, 256, 0, stream>>>(x1, xyT, muX, muY, sumX_f, sumY_f, yy_f, SSEs);
  k_loss_big<<<dim3(8, 25), 256, 0, stream>>>(x1, Gv, SSEb);
  k_loss_final<<<1, 64, 0, stream>>>(SSEs, SSEb, out, aidx);
  k_outW<<<DIM * ODIM / 256, 256, 0, stream>>>(x0, aidx, out);
  k_outB<<<ODIM, 64, 0, stream>>>(x0, muX, muY, aidx, out);
}

// Round 6
// 465.610 us; speedup vs baseline: 1.7877x; 1.1085x over previous
//
#include <hip/hip_runtime.h>
#include <stdint.h>

#define NROWS 50000
#define DIM   512
#define ODIM  256
#define FOLDS 5
#define FOLD  10000
#define NTR   40000
#define CHKG  2000
#define NCHUNK 5

__constant__ float c_lam[5] = {0.01f, 0.1f, 1.0f, 10.0f, 100.0f};
// tile pairs for fused gram: 10 xx upper-triangle + 8 xy (A=Y rows 512+, B=X rows)
__constant__ int c_pA[18] = {0,0,0,0,128,128,128,256,256,384, 512,512,512,512,640,640,640,640};
__constant__ int c_pB[18] = {0,128,256,384,128,256,384,256,384,384, 0,128,256,384,0,128,256,384};

typedef __attribute__((ext_vector_type(8))) short short8;
typedef __attribute__((ext_vector_type(4))) float floatx4;

__device__ __forceinline__ unsigned short f2bf(float f) {
  unsigned u = __float_as_uint(f);
  u += 0x7FFFu + ((u >> 16) & 1u);          // RNE
  return (unsigned short)(u >> 16);
}
__device__ __forceinline__ float bf2f(unsigned short h) {
  return __uint_as_float(((unsigned)h) << 16);
}

__device__ __forceinline__ float block_sum256(float v) {
  __shared__ float red[4];
  for (int off = 32; off; off >>= 1) v += __shfl_down(v, off, 64);
  if ((threadIdx.x & 63) == 0) red[threadIdx.x >> 6] = v;
  __syncthreads();
  float r = 0.f;
  if (threadIdx.x == 0) r = red[0] + red[1] + red[2] + red[3];
  return r;
}

// ---------- transpose X [50000,512] f32 -> ZT rows [0,512) bf16 ----------
__global__ __launch_bounds__(256) void k_tX(const float* __restrict__ X,
                                            unsigned short* __restrict__ ZT) {
  __shared__ unsigned short lds[64][72];
  int n0 = blockIdx.x * 64, d0 = blockIdx.y * 64;
  int t = threadIdx.x;
  #pragma unroll
  for (int p = 0; p < 4; ++p) {
    int r = p * 16 + (t >> 4);
    int c = (t & 15) * 4;
    int n = n0 + r;
    float4 v = make_float4(0.f, 0.f, 0.f, 0.f);
    if (n < NROWS) v = *(const float4*)(X + (size_t)n * DIM + d0 + c);
    lds[c + 0][r] = f2bf(v.x);
    lds[c + 1][r] = f2bf(v.y);
    lds[c + 2][r] = f2bf(v.z);
    lds[c + 3][r] = f2bf(v.w);
  }
  __syncthreads();
  #pragma unroll
  for (int p = 0; p < 2; ++p) {
    int d = p * 32 + (t >> 3);
    int nc = (t & 7) * 8;
    if (n0 + nc < NROWS) {
      uint4 v = *(const uint4*)&lds[d][nc];
      *(uint4*)(ZT + (size_t)(d0 + d) * NROWS + n0 + nc) = v;
    }
  }
}

// ---------- transpose Y [50000,256] f32 -> ZT rows [512,768) bf16 ----------
__global__ __launch_bounds__(256) void k_tY(const float* __restrict__ Y,
                                            unsigned short* __restrict__ ZT) {
  __shared__ unsigned short lds[64][72];
  int n0 = blockIdx.x * 64, d0 = blockIdx.y * 64;
  int t = threadIdx.x;
  #pragma unroll
  for (int p = 0; p < 4; ++p) {
    int r = p * 16 + (t >> 4);
    int c = (t & 15) * 4;
    int n = n0 + r;
    float4 v = make_float4(0.f, 0.f, 0.f, 0.f);
    if (n < NROWS) v = *(const float4*)(Y + (size_t)n * ODIM + d0 + c);
    lds[c + 0][r] = f2bf(v.x);
    lds[c + 1][r] = f2bf(v.y);
    lds[c + 2][r] = f2bf(v.z);
    lds[c + 3][r] = f2bf(v.w);
  }
  __syncthreads();
  #pragma unroll
  for (int p = 0; p < 2; ++p) {
    int d = p * 32 + (t >> 3);
    int nc = (t & 7) * 8;
    if (n0 + nc < NROWS) {
      uint4 v = *(const uint4*)&lds[d][nc];
      *(uint4*)(ZT + (size_t)(512 + d0 + d) * NROWS + n0 + nc) = v;
    }
  }
}

// ---------- per-fold column sums of X (from ZT rows 0..511) ----------
__global__ __launch_bounds__(64) void k_sumX(const unsigned short* __restrict__ ZT,
                                             float* __restrict__ sumX_f) {
  int seg = blockIdx.x;            // k*512 + d
  int k = seg / DIM, d = seg % DIM;
  const unsigned short* row = ZT + (size_t)d * NROWS + k * FOLD;
  float s = 0.f;
  for (int i = threadIdx.x * 4; i < FOLD; i += 64 * 4) {
    ushort4 v = *(const ushort4*)(row + i);
    s += bf2f(v.x) + bf2f(v.y) + bf2f(v.z) + bf2f(v.w);
  }
  for (int off = 32; off; off >>= 1) s += __shfl_down(s, off, 64);
  if (threadIdx.x == 0) sumX_f[seg] = s;
}

// ---------- per-fold sums of Y and sum of Y^2 ----------
__global__ __launch_bounds__(256) void k_sumY(const float* __restrict__ Y,
                                              float* __restrict__ sumY_f,
                                              float* __restrict__ yy_f) {
  __shared__ float sh[4][ODIM];
  int k = blockIdx.x, ch = blockIdx.y;
  int lane = threadIdx.x & 63, grp = threadIdx.x >> 6;
  int nbeg = k * FOLD + ch * 80;
  float s0 = 0.f, s1 = 0.f, s2 = 0.f, s3 = 0.f, q = 0.f;
  #pragma unroll 4
  for (int r = 0; r < 80; r += 4) {
    int n = nbeg + r + grp;
    float4 v = *(const float4*)(Y + (size_t)n * ODIM + lane * 4);
    s0 += v.x; s1 += v.y; s2 += v.z; s3 += v.w;
    q += v.x * v.x + v.y * v.y + v.z * v.z + v.w * v.w;
  }
  sh[grp][lane * 4 + 0] = s0;
  sh[grp][lane * 4 + 1] = s1;
  sh[grp][lane * 4 + 2] = s2;
  sh[grp][lane * 4 + 3] = s3;
  __syncthreads();
  int o = threadIdx.x;
  float t = sh[0][o] + sh[1][o] + sh[2][o] + sh[3][o];
  atomicAdd(&sumY_f[k * ODIM + o], t);
  float qt = block_sum256(q);
  if (threadIdx.x == 0) atomicAdd(&yy_f[k], qt);
}

// ---------- MFMA inner step: D += A*B over K=64 staged in LDS ----------
__device__ __forceinline__ void mfma_step(const unsigned short (*A)[72],
                                          const unsigned short (*B)[72],
                                          int wm, int wn, int lane,
                                          floatx4 acc[4][4]) {
  int fr = lane & 15;
  int fq = (lane >> 4) * 8;
  #pragma unroll
  for (int kk = 0; kk < 64; kk += 32) {
    short8 af[4], bfv[4];
    #pragma unroll
    for (int mt = 0; mt < 4; ++mt)
      af[mt] = *(const short8*)&A[wm + mt * 16 + fr][kk + fq];
    #pragma unroll
    for (int nt = 0; nt < 4; ++nt)
      bfv[nt] = *(const short8*)&B[wn + nt * 16 + fr][kk + fq];
    #pragma unroll
    for (int mt = 0; mt < 4; ++mt)
      #pragma unroll
      for (int nt = 0; nt < 4; ++nt)
        acc[mt][nt] = __builtin_amdgcn_mfma_f32_16x16x32_bf16(af[mt], bfv[nt], acc[mt][nt], 0, 0, 0);
  }
}

// ---------- fused per-fold Gram over ZT=[XT;YT]: partial tiles, NO atomics ----------
__global__ __launch_bounds__(256, 2) void k_gram(const unsigned short* __restrict__ ZT,
                                                 float* __restrict__ part) {
  __shared__ unsigned short Ab[128][72];
  __shared__ unsigned short Bb[128][72];
  int p = blockIdx.x, f = blockIdx.y, c = blockIdx.z;
  int i0 = c_pA[p], j0 = c_pB[p];
  int kbeg = c * CHKG, kend = kbeg + CHKG;
  size_t basek = (size_t)f * FOLD;
  int t = threadIdx.x, lane = t & 63, w = t >> 6;
  int wm = (w & 1) * 64, wn = (w >> 1) * 64;
  floatx4 acc[4][4];
  #pragma unroll
  for (int a = 0; a < 4; ++a)
    #pragma unroll
    for (int b = 0; b < 4; ++b) acc[a][b] = (floatx4)0.f;
  for (int ks = kbeg; ks < kend; ks += 64) {
    #pragma unroll
    for (int q = 0; q < 4; ++q) {
      int lin = t + q * 256;
      int row = lin >> 3, col8 = (lin & 7) * 8;
      int gk = ks + col8;
      uint4 va = make_uint4(0, 0, 0, 0), vb = va;
      if (gk < kend) {
        va = *(const uint4*)(ZT + (size_t)(i0 + row) * NROWS + basek + gk);
        vb = *(const uint4*)(ZT + (size_t)(j0 + row) * NROWS + basek + gk);
      }
      *(uint4*)&Ab[row][col8] = va;
      *(uint4*)&Bb[row][col8] = vb;
    }
    __syncthreads();
    mfma_step(Ab, Bb, wm, wn, lane, acc);
    __syncthreads();
  }
  float* outp = part + (((size_t)p * 5 + f) * NCHUNK + c) * 16384;
  #pragma unroll
  for (int mt = 0; mt < 4; ++mt)
    #pragma unroll
    for (int nt = 0; nt < 4; ++nt)
      #pragma unroll
      for (int i = 0; i < 4; ++i) {
        int rr = wm + mt * 16 + ((lane >> 4) * 4 + i);
        int cc = wn + nt * 16 + (lane & 15);
        outp[rr * 128 + cc] = acc[mt][nt][i];
      }
}

// ---------- reduce K-chunk partials -> xxT (upper-tri pairs) / xyT ----------
__global__ __launch_bounds__(256) void k_red(const float* __restrict__ part,
                                             float* __restrict__ xxT,
                                             float* __restrict__ xyT) {
  int b = blockIdx.x;                   // 18*5*64 = 5760
  int tile = b >> 6;
  int e = ((b & 63) << 8) + threadIdx.x;
  int p = tile / 5, f = tile % 5;
  const float* src = part + ((size_t)(p * 5 + f) * NCHUNK) * 16384 + e;
  float s = 0.f;
  #pragma unroll
  for (int c = 0; c < NCHUNK; ++c) s += src[(size_t)c * 16384];
  int rr = e >> 7, cc = e & 127;
  int i0 = c_pA[p], j0 = c_pB[p];
  if (p < 10) xxT[(size_t)f * DIM * DIM + (i0 + rr) * DIM + (j0 + cc)] = s;
  else        xyT[(size_t)f * ODIM * DIM + (i0 - 512 + rr) * DIM + (j0 + cc)] = s;
}

// ---------- train means (5 LOO + full) ----------
__global__ void k_means(const float* __restrict__ sumX_f, const float* __restrict__ sumY_f,
                        float* __restrict__ muX, float* __restrict__ muY) {
  int g = blockIdx.x * 256 + threadIdx.x;
  if (g < 6 * DIM) {
    int k = g / DIM, d = g % DIM;
    float s = 0.f;
    #pragma unroll
    for (int kk = 0; kk < 5; ++kk) s += sumX_f[kk * DIM + d];
    muX[g] = (k < 5) ? (s - sumX_f[k * DIM + d]) / (float)NTR : s / (float)NROWS;
  } else {
    int g2 = g - 6 * DIM;
    int k = g2 / ODIM, o = g2 % ODIM;
    float s = 0.f;
    #pragma unroll
    for (int kk = 0; kk < 5; ++kk) s += sumY_f[kk * ODIM + o];
    muY[g2] = (k < 5) ? (s - sumY_f[k * ODIM + o]) / (float)NTR : s / (float)NROWS;
  }
}

// ---------- assemble A_k (bf16) + Gv (bf16); xxT stored upper-tri, mirror on read ----------
__global__ void k_asmA(const float* __restrict__ xxT, const float* __restrict__ muX,
                       unsigned short* __restrict__ Abf, unsigned short* __restrict__ Gv) {
  size_t g = (size_t)blockIdx.x * 256 + threadIdx.x;     // < 6*512*512
  int k = (int)(g / (DIM * DIM));
  int r = (int)(g % (DIM * DIM));
  int d = r / DIM, e = r % DIM;
  int ridx = (d <= e) ? r : (e * DIM + d);
  float s = 0.f;
  #pragma unroll
  for (int kk = 0; kk < 5; ++kk) s += xxT[(size_t)kk * DIM * DIM + ridx];
  float v;
  if (k < 5) {
    float own = xxT[(size_t)k * DIM * DIM + ridx];
    v = s - own - (float)NTR * muX[k * DIM + d] * muX[k * DIM + e];
    Gv[(size_t)k * DIM * DIM + r] = f2bf(own);
  } else {
    v = s - (float)NROWS * muX[5 * DIM + d] * muX[5 * DIM + e];
  }
  Abf[g] = f2bf(v);
}

// ---------- assemble B_k^T [k][o][d] f32 and init x0 for all 30 systems ----------
__global__ void k_asmB(const float* __restrict__ xyT, const float* __restrict__ muX,
                       const float* __restrict__ muY, float* __restrict__ BT,
                       unsigned short* __restrict__ x0) {
  int g = blockIdx.x * 256 + threadIdx.x;                // < 6*256*512
  int k = g / (ODIM * DIM);
  int r = g % (ODIM * DIM);
  int o = r / DIM, d = r % DIM;
  float s = 0.f;
  #pragma unroll
  for (int kk = 0; kk < 5; ++kk) s += xyT[(size_t)kk * ODIM * DIM + r];
  float v;
  if (k < 5) v = s - xyT[(size_t)k * ODIM * DIM + r] - (float)NTR * muY[k * ODIM + o] * muX[k * DIM + d];
  else       v = s - (float)NROWS * muY[5 * ODIM + o] * muX[5 * DIM + d];
  BT[g] = v;
  float halfsum = (k < 5) ? 40750.f : 50750.f;           // (a+b)/2 spectral midpoint
  #pragma unroll
  for (int l = 0; l < 5; ++l) {
    float th = halfsum + c_lam[l];
    x0[(size_t)(l * 6 + k) * (ODIM * DIM) + r] = f2bf(v / th);
  }
}

// ---------- one Richardson sweep; k5only=1 restricts to the 5 full-data systems ----------
__global__ __launch_bounds__(256, 2) void k_rich(const unsigned short* __restrict__ xin,
                                                 unsigned short* __restrict__ xout,
                                                 const unsigned short* __restrict__ Abf,
                                                 const float* __restrict__ BT,
                                                 int k5only) {
  __shared__ unsigned short Xb[128][72];
  __shared__ unsigned short Mb[128][72];
  int tile = blockIdx.x;
  int o0 = (tile & 1) * 128, d0 = (tile >> 1) * 128;
  int s = k5only ? (blockIdx.y * 6 + 5) : blockIdx.y;
  int k = s % 6, l = s / 6;
  float lam = c_lam[l];
  float absum = (k < 5) ? 81500.f : 101500.f;
  float alpha = 2.f / (absum + 2.f * lam);
  const unsigned short* xs = xin + (size_t)s * ODIM * DIM;
  const unsigned short* Am = Abf + (size_t)k * DIM * DIM;
  int t = threadIdx.x, lane = t & 63, w = t >> 6;
  int wm = (w & 1) * 64, wn = (w >> 1) * 64;
  floatx4 acc[4][4];
  #pragma unroll
  for (int a = 0; a < 4; ++a)
    #pragma unroll
    for (int b = 0; b < 4; ++b) acc[a][b] = (floatx4)0.f;
  for (int ks = 0; ks < DIM; ks += 64) {
    #pragma unroll
    for (int q = 0; q < 4; ++q) {
      int lin = t + q * 256;
      int row = lin >> 3, col8 = (lin & 7) * 8;
      *(uint4*)&Xb[row][col8] = *(const uint4*)(xs + (size_t)(o0 + row) * DIM + ks + col8);
      *(uint4*)&Mb[row][col8] = *(const uint4*)(Am + (size_t)(d0 + row) * DIM + ks + col8);
    }
    __syncthreads();
    mfma_step(Xb, Mb, wm, wn, lane, acc);
    __syncthreads();
  }
  const float* Bk = BT + (size_t)k * ODIM * DIM;
  unsigned short* xo = xout + (size_t)s * ODIM * DIM;
  #pragma unroll
  for (int mt = 0; mt < 4; ++mt)
    #pragma unroll
    for (int nt = 0; nt < 4; ++nt)
      #pragma unroll
      for (int i = 0; i < 4; ++i) {
        int ro = o0 + wm + mt * 16 + ((lane >> 4) * 4 + i);
        int cd = d0 + wn + nt * 16 + (lane & 15);
        int idx = ro * DIM + cd;
        float xold = bf2f(xs[idx]);
        float r = Bk[idx] - acc[mt][nt][i] - lam * xold;
        xo[idx] = f2bf(xold + alpha * r);
      }
}

// ---------- tr(W^T Gv W) via GEMM + dot, atomic per (l,k) ----------
__global__ __launch_bounds__(256, 2) void k_loss_big(const unsigned short* __restrict__ x,
                                                     const unsigned short* __restrict__ Gv,
                                                     float* __restrict__ SSEb) {
  __shared__ unsigned short Xb[128][72];
  __shared__ unsigned short Mb[128][72];
  int tile = blockIdx.x;
  int o0 = (tile & 1) * 128, d0 = (tile >> 1) * 128;
  int s25 = blockIdx.y;
  int k = s25 % 5, l = s25 / 5;
  int s = l * 6 + k;
  const unsigned short* xs = x + (size_t)s * ODIM * DIM;
  const unsigned short* Gm = Gv + (size_t)k * DIM * DIM;
  int t = threadIdx.x, lane = t & 63, w = t >> 6;
  int wm = (w & 1) * 64, wn = (w >> 1) * 64;
  floatx4 acc[4][4];
  #pragma unroll
  for (int a = 0; a < 4; ++a)
    #pragma unroll
    for (int b = 0; b < 4; ++b) acc[a][b] = (floatx4)0.f;
  for (int ks = 0; ks < DIM; ks += 64) {
    #pragma unroll
    for (int q = 0; q < 4; ++q) {
      int lin = t + q * 256;
      int row = lin >> 3, col8 = (lin & 7) * 8;
      *(uint4*)&Xb[row][col8] = *(const uint4*)(xs + (size_t)(o0 + row) * DIM + ks + col8);
      *(uint4*)&Mb[row][col8] = *(const uint4*)(Gm + (size_t)(d0 + row) * DIM + ks + col8);
    }
    __syncthreads();
    mfma_step(Xb, Mb, wm, wn, lane, acc);
    __syncthreads();
  }
  float part = 0.f;
  #pragma unroll
  for (int mt = 0; mt < 4; ++mt)
    #pragma unroll
    for (int nt = 0; nt < 4; ++nt)
      #pragma unroll
      for (int i = 0; i < 4; ++i) {
        int ro = o0 + wm + mt * 16 + ((lane >> 4) * 4 + i);
        int cd = d0 + wn + nt * 16 + (lane & 15);
        part += acc[mt][nt][i] * bf2f(xs[ro * DIM + cd]);
      }
  float tot = block_sum256(part);
  if (threadIdx.x == 0) atomicAdd(&SSEb[s25], tot);
}

// ---------- linear/const SSE terms per (l,k) ----------
__global__ __launch_bounds__(256) void k_loss_small(const unsigned short* __restrict__ x,
                                                    const float* __restrict__ xyT,
                                                    const float* __restrict__ muX,
                                                    const float* __restrict__ muY,
                                                    const float* __restrict__ sumX_f,
                                                    const float* __restrict__ sumY_f,
                                                    const float* __restrict__ yy_f,
                                                    float* __restrict__ SSEs) {
  __shared__ float lmu[DIM];
  __shared__ float lsx[DIM];
  int s25 = blockIdx.x;
  int k = s25 % 5, l = s25 / 5;
  int sidx = l * 6 + k;
  int o = threadIdx.x;
  lmu[o] = muX[k * DIM + o];       lmu[o + 256] = muX[k * DIM + o + 256];
  lsx[o] = sumX_f[k * DIM + o];    lsx[o + 256] = sumX_f[k * DIM + o + 256];
  __syncthreads();
  const unsigned short* xr = x + (size_t)sidx * ODIM * DIM + (size_t)o * DIM;
  const float* cv = xyT + (size_t)k * ODIM * DIM + (size_t)o * DIM;
  float t1 = 0.f, t2 = 0.f, trc = 0.f;
  for (int d = 0; d < DIM; d += 4) {
    ushort4 xv = *(const ushort4*)(xr + d);
    float4 cf = *(const float4*)(cv + d);
    float a0 = bf2f(xv.x), a1 = bf2f(xv.y), a2 = bf2f(xv.z), a3 = bf2f(xv.w);
    t1 += a0 * lsx[d] + a1 * lsx[d + 1] + a2 * lsx[d + 2] + a3 * lsx[d + 3];
    t2 += a0 * lmu[d] + a1 * lmu[d + 1] + a2 * lmu[d + 2] + a3 * lmu[d + 3];
    trc += a0 * cf.x + a1 * cf.y + a2 * cf.z + a3 * cf.w;
  }
  float b = muY[k * ODIM + o] - t2;
  float syv = sumY_f[k * ODIM + o];
  float part = 2.f * b * t1 + (float)FOLD * b * b - 2.f * trc - 2.f * b * syv;
  float tot = block_sum256(part);
  if (threadIdx.x == 0) SSEs[s25] = tot + yy_f[k];
}

// ---------- losses + argmin ----------
__global__ void k_loss_final(const float* __restrict__ SSEs, const float* __restrict__ SSEb,
                             float* __restrict__ out, int* __restrict__ aidx) {
  if (threadIdx.x == 0) {
    float best = 1e30f; int bi = 0;
    for (int l = 0; l < 5; ++l) {
      float s = 0.f;
      for (int k = 0; k < 5; ++k) s += SSEs[l * 5 + k] + SSEb[l * 5 + k];
      float loss = s / (float)(FOLDS * FOLD * ODIM);
      out[131072 + 256 + l] = loss;
      if (loss < best) { best = loss; bi = l; }
    }
    aidx[0] = bi;
  }
}

// ---------- outputs ----------
__global__ void k_outW(const unsigned short* __restrict__ x, const int* __restrict__ aidx,
                       float* __restrict__ out) {
  int g = blockIdx.x * 256 + threadIdx.x;
  int s = aidx[0] * 6 + 5;
  out[g] = bf2f(x[(size_t)s * ODIM * DIM + g]);
}

__global__ __launch_bounds__(64) void k_outB(const unsigned short* __restrict__ x,
                                             const float* __restrict__ muX,
                                             const float* __restrict__ muY,
                                             const int* __restrict__ aidx,
                                             float* __restrict__ out) {
  int o = blockIdx.x, lane = threadIdx.x;
  int s = aidx[0] * 6 + 5;
  const unsigned short* xr = x + (size_t)s * ODIM * DIM + (size_t)o * DIM;
  float dsum = 0.f;
  for (int d = lane; d < DIM; d += 64) dsum += bf2f(xr[d]) * muX[5 * DIM + d];
  for (int off = 32; off; off >>= 1) dsum += __shfl_down(dsum, off, 64);
  if (lane == 0) out[131072 + o] = muY[5 * ODIM + o] - dsum;
}

extern "C" void kernel_launch(void* const* d_in, const int* in_sizes, int n_in,
                              void* d_out, int out_size, void* d_ws, size_t ws_size,
                              hipStream_t stream) {
  const float* X = (const float*)d_in[0];
  const float* Y = (const float*)d_in[1];
  float* out = (float*)d_out;
  char* ws = (char*)d_ws;
  size_t off = 0;
  auto alloc = [&](size_t bytes) {
    size_t cur = off;
    off = (off + bytes + 255) & ~(size_t)255;
    return cur;
  };
  unsigned short* ZT = (unsigned short*)(ws + alloc((size_t)768 * NROWS * 2));
  float* xxT    = (float*)(ws + alloc((size_t)5 * DIM * DIM * 4));
  float* xyT    = (float*)(ws + alloc((size_t)5 * ODIM * DIM * 4));
  float* sumX_f = (float*)(ws + alloc(5 * DIM * 4));
  float* muX    = (float*)(ws + alloc(6 * DIM * 4));
  float* muY    = (float*)(ws + alloc(6 * ODIM * 4));
  float* SSEs   = (float*)(ws + alloc(25 * 4));
  int* aidx     = (int*)(ws + alloc(4));
  size_t zbeg = off;
  float* sumY_f = (float*)(ws + alloc(5 * ODIM * 4));
  float* yy_f   = (float*)(ws + alloc(5 * 4));
  float* SSEb   = (float*)(ws + alloc(25 * 4));
  size_t zend = off;
  // union region: partial tiles (29.5 MB) reused later by Abf/Gv/BT/x0/x1 (24.7 MB)
  char* ub = ws + alloc((size_t)18 * 5 * NCHUNK * 16384 * 4);
  float* part = (float*)ub;
  unsigned short* Abf = (unsigned short*)ub;                 // 6*512*512*2 = 3,145,728
  unsigned short* Gv  = Abf + (size_t)6 * DIM * DIM;         // +2,621,440
  float* BT           = (float*)(Gv + (size_t)5 * DIM * DIM);// +3,145,728
  unsigned short* x0  = (unsigned short*)(BT + (size_t)6 * ODIM * DIM); // +7,864,320
  unsigned short* x1  = x0 + (size_t)30 * ODIM * DIM;        // +7,864,320 = 24,641,536 total

  hipMemsetAsync(ws + zbeg, 0, zend - zbeg, stream);

  k_tX<<<dim3(782, 8), 256, 0, stream>>>(X, ZT);
  k_tY<<<dim3(782, 4), 256, 0, stream>>>(Y, ZT);
  k_sumX<<<5 * DIM, 64, 0, stream>>>(ZT, sumX_f);
  k_sumY<<<dim3(5, 125), 256, 0, stream>>>(Y, sumY_f, yy_f);
  k_gram<<<dim3(18, 5, NCHUNK), 256, 0, stream>>>(ZT, part);
  k_red<<<18 * 5 * 64, 256, 0, stream>>>(part, xxT, xyT);
  k_means<<<18, 256, 0, stream>>>(sumX_f, sumY_f, muX, muY);
  k_asmA<<<6 * DIM * DIM / 256, 256, 0, stream>>>(xxT, muX, Abf, Gv);
  k_asmB<<<6 * ODIM * DIM / 256, 256, 0, stream>>>(xyT, muX, muY, BT, x0);
  // sweeps: 3 over all 30 systems, +1 over the 5 full-data (k=5) systems.
  // CV final state lands in x1; full-data final state lands in x0.
  k_rich<<<dim3(8, 30), 256, 0, stream>>>(x0, x1, Abf, BT, 0);
  k_rich<<<dim3(8, 30), 256, 0, stream>>>(x1, x0, Abf, BT, 0);
  k_rich<<<dim3(8, 30), 256, 0, stream>>>(x0, x1, Abf, BT, 0);
  k_rich<<<dim3(8, 5),  256, 0, stream>>>(x1, x0, Abf, BT, 1);
  k_loss_small<<<25, 256, 0, stream>>>(x1, xyT, muX, muY, sumX_f, sumY_f, yy_f, SSEs);
  k_loss_big<<<dim3(8, 25), 256, 0, stream>>>(x1, Gv, SSEb);
  k_loss_final<<<1, 64, 0, stream>>>(SSEs, SSEb, out, aidx);
  k_outW<<<DIM * ODIM / 256, 256, 0, stream>>>(x0, aidx, out);
  k_outB<<<ODIM, 64, 0, stream>>>(x0, muX, muY, aidx, out);
}

// Round 7
// 422.778 us; speedup vs baseline: 1.9689x; 1.1013x over previous
//
#include <hip/hip_runtime.h>
#include <stdint.h>

#define NROWS 50000
#define DIM   512
#define ODIM  256
#define FOLDS 5
#define FOLD  10000
#define FOLDP 10048            // fold padded to multiple of 64 (48 zero cols)
#define ZROW  (5 * FOLDP)      // 50240 elements per ZT row
#define NTR   40000
#define NCHUNK 5               // K-chunks per fold: 2048 x4 + 1856

__constant__ float c_lam[5] = {0.01f, 0.1f, 1.0f, 10.0f, 100.0f};
// tile pairs for fused gram: 10 xx upper-triangle + 8 xy (A=Y rows 512+, B=X rows)
__constant__ int c_pA[18] = {0,0,0,0,128,128,128,256,256,384, 512,512,512,512,640,640,640,640};
__constant__ int c_pB[18] = {0,128,256,384,128,256,384,256,384,384, 0,128,256,384,0,128,256,384};

typedef __attribute__((ext_vector_type(8))) short short8;
typedef __attribute__((ext_vector_type(4))) float floatx4;

__device__ __forceinline__ unsigned short f2bf(float f) {
  unsigned u = __float_as_uint(f);
  u += 0x7FFFu + ((u >> 16) & 1u);          // RNE
  return (unsigned short)(u >> 16);
}
__device__ __forceinline__ float bf2f(unsigned short h) {
  return __uint_as_float(((unsigned)h) << 16);
}

// async global->LDS DMA, 16 B per lane; LDS dest = wave-uniform base + lane*16
__device__ __forceinline__ void gload_lds(const unsigned short* g, unsigned short* l) {
  __builtin_amdgcn_global_load_lds(
      (const __attribute__((address_space(1))) unsigned int*)g,
      (__attribute__((address_space(3))) unsigned int*)l, 16, 0, 0);
}

__device__ __forceinline__ float block_sum256(float v) {
  __shared__ float red[4];
  for (int off = 32; off; off >>= 1) v += __shfl_down(v, off, 64);
  if ((threadIdx.x & 63) == 0) red[threadIdx.x >> 6] = v;
  __syncthreads();
  float r = 0.f;
  if (threadIdx.x == 0) r = red[0] + red[1] + red[2] + red[3];
  return r;
}

// ---------- zero the 48-col pads at the end of each fold in ZT ----------
__global__ __launch_bounds__(256) void k_padZ(unsigned short* __restrict__ ZT) {
  int row = blockIdx.x;          // 768
  int t = threadIdx.x;
  if (t < 240) {
    int k = t / 48, j = t % 48;
    ZT[(size_t)row * ZROW + k * FOLDP + FOLD + j] = 0;
  }
}

// ---------- transpose X|Y [50000,*] f32 -> ZT bf16 (fold-padded cols) ----------
__global__ __launch_bounds__(256) void k_tXY(const float* __restrict__ X,
                                             const float* __restrict__ Y,
                                             unsigned short* __restrict__ ZT) {
  __shared__ unsigned short lds[64][72];
  int by = blockIdx.y;
  const float* src = (by < 8) ? X : Y;
  int srcld = (by < 8) ? DIM : ODIM;
  int dsrc0 = (by < 8) ? by * 64 : (by - 8) * 64;
  int dst0 = (by < 8) ? dsrc0 : 512 + dsrc0;
  int n0 = blockIdx.x * 64;
  int t = threadIdx.x;
  #pragma unroll
  for (int p = 0; p < 4; ++p) {
    int r = p * 16 + (t >> 4);
    int c = (t & 15) * 4;
    int n = n0 + r;
    float4 v = make_float4(0.f, 0.f, 0.f, 0.f);
    if (n < NROWS) v = *(const float4*)(src + (size_t)n * srcld + dsrc0 + c);
    lds[c + 0][r] = f2bf(v.x);
    lds[c + 1][r] = f2bf(v.y);
    lds[c + 2][r] = f2bf(v.z);
    lds[c + 3][r] = f2bf(v.w);
  }
  __syncthreads();
  #pragma unroll
  for (int p = 0; p < 2; ++p) {
    int d = p * 32 + (t >> 3);
    int nc = (t & 7) * 8;
    int n = n0 + nc;
    if (n < NROWS) {
      int col = (n / FOLD) * FOLDP + n % FOLD;   // 8-wide writes never straddle a fold pad
      uint4 v = *(const uint4*)&lds[d][nc];
      *(uint4*)(ZT + (size_t)(dst0 + d) * ZROW + col) = v;
    }
  }
}

// ---------- per-fold column sums of X (from ZT rows 0..511; pad zeros harmless) ----------
__global__ __launch_bounds__(64) void k_sumX(const unsigned short* __restrict__ ZT,
                                             float* __restrict__ sumX_f) {
  int seg = blockIdx.x;            // k*512 + d
  int k = seg / DIM, d = seg % DIM;
  const unsigned short* row = ZT + (size_t)d * ZROW + k * FOLDP;
  float s = 0.f;
  for (int i = threadIdx.x * 4; i < FOLDP; i += 64 * 4) {
    ushort4 v = *(const ushort4*)(row + i);
    s += bf2f(v.x) + bf2f(v.y) + bf2f(v.z) + bf2f(v.w);
  }
  for (int off = 32; off; off >>= 1) s += __shfl_down(s, off, 64);
  if (threadIdx.x == 0) sumX_f[seg] = s;
}

// ---------- per-fold sums of Y and sum of Y^2 ----------
__global__ __launch_bounds__(256) void k_sumY(const float* __restrict__ Y,
                                              float* __restrict__ sumY_f,
                                              float* __restrict__ yy_f) {
  __shared__ float sh[4][ODIM];
  int k = blockIdx.x, ch = blockIdx.y;
  int lane = threadIdx.x & 63, grp = threadIdx.x >> 6;
  int nbeg = k * FOLD + ch * 80;
  float s0 = 0.f, s1 = 0.f, s2 = 0.f, s3 = 0.f, q = 0.f;
  #pragma unroll 4
  for (int r = 0; r < 80; r += 4) {
    int n = nbeg + r + grp;
    float4 v = *(const float4*)(Y + (size_t)n * ODIM + lane * 4);
    s0 += v.x; s1 += v.y; s2 += v.z; s3 += v.w;
    q += v.x * v.x + v.y * v.y + v.z * v.z + v.w * v.w;
  }
  sh[grp][lane * 4 + 0] = s0;
  sh[grp][lane * 4 + 1] = s1;
  sh[grp][lane * 4 + 2] = s2;
  sh[grp][lane * 4 + 3] = s3;
  __syncthreads();
  int o = threadIdx.x;
  float t = sh[0][o] + sh[1][o] + sh[2][o] + sh[3][o];
  atomicAdd(&sumY_f[k * ODIM + o], t);
  float qt = block_sum256(q);
  if (threadIdx.x == 0) atomicAdd(&yy_f[k], qt);
}

// ---------- MFMA inner step over swizzled LDS (phys col8 = log col8 ^ (row&7)) ----------
__device__ __forceinline__ void mfma_step(const unsigned short (*A)[64],
                                          const unsigned short (*B)[64],
                                          int wm, int wn, int lane,
                                          floatx4 acc[4][4]) {
  int fr = lane & 15;
  int fq = (lane >> 4) * 8;
  #pragma unroll
  for (int kk = 0; kk < 64; kk += 32) {
    int K8 = (kk + fq) >> 3;
    short8 af[4], bfv[4];
    #pragma unroll
    for (int mt = 0; mt < 4; ++mt) {
      int row = wm + mt * 16 + fr;
      af[mt] = *(const short8*)&A[row][(K8 ^ (row & 7)) * 8];
    }
    #pragma unroll
    for (int nt = 0; nt < 4; ++nt) {
      int row = wn + nt * 16 + fr;
      bfv[nt] = *(const short8*)&B[row][(K8 ^ (row & 7)) * 8];
    }
    #pragma unroll
    for (int mt = 0; mt < 4; ++mt)
      #pragma unroll
      for (int nt = 0; nt < 4; ++nt)
        acc[mt][nt] = __builtin_amdgcn_mfma_f32_16x16x32_bf16(af[mt], bfv[nt], acc[mt][nt], 0, 0, 0);
  }
}

// ---------- fused per-fold Gram over ZT=[XT;YT]: async staged, no atomics ----------
__global__ __launch_bounds__(256, 2) void k_gram(const unsigned short* __restrict__ ZT,
                                                 float* __restrict__ part) {
  __shared__ unsigned short Ab[128][64];
  __shared__ unsigned short Bb[128][64];
  int p = blockIdx.x, f = blockIdx.y, c = blockIdx.z;
  int i0 = c_pA[p], j0 = c_pB[p];
  int nsteps = (c < 4) ? 32 : 29;
  size_t kbase = (size_t)f * FOLDP + ((c < 4) ? c * 2048 : 8192);
  int t = threadIdx.x, lane = t & 63, w = t >> 6;
  int wm = (w & 1) * 64, wn = (w >> 1) * 64;
  int srow = w * 32 + (lane >> 3);
  int scol = ((lane & 7) ^ (lane >> 3)) * 8;           // swizzled source col (shorts)
  const unsigned short* gA = ZT + (size_t)(i0 + srow) * ZROW + kbase + scol;
  const unsigned short* gB = ZT + (size_t)(j0 + srow) * ZROW + kbase + scol;
  floatx4 acc[4][4];
  #pragma unroll
  for (int a = 0; a < 4; ++a)
    #pragma unroll
    for (int b = 0; b < 4; ++b) acc[a][b] = (floatx4)0.f;
  for (int s = 0; s < nsteps; ++s) {
    #pragma unroll
    for (int q = 0; q < 4; ++q) {
      gload_lds(gA + (size_t)q * 8 * ZROW, &Ab[w * 32 + q * 8][0]);
      gload_lds(gB + (size_t)q * 8 * ZROW, &Bb[w * 32 + q * 8][0]);
    }
    gA += 64; gB += 64;
    __syncthreads();
    mfma_step(Ab, Bb, wm, wn, lane, acc);
    __syncthreads();
  }
  float* outp = part + (((size_t)p * 5 + f) * NCHUNK + c) * 16384;
  #pragma unroll
  for (int mt = 0; mt < 4; ++mt)
    #pragma unroll
    for (int nt = 0; nt < 4; ++nt)
      #pragma unroll
      for (int i = 0; i < 4; ++i) {
        int rr = wm + mt * 16 + ((lane >> 4) * 4 + i);
        int cc = wn + nt * 16 + (lane & 15);
        outp[rr * 128 + cc] = acc[mt][nt][i];
      }
}

// ---------- reduce K-chunk partials -> xxT (upper-tri pairs) / xyT ----------
__global__ __launch_bounds__(256) void k_red(const float* __restrict__ part,
                                             float* __restrict__ xxT,
                                             float* __restrict__ xyT) {
  int b = blockIdx.x;                   // 18*5*64 = 5760
  int tile = b >> 6;
  int e = ((b & 63) << 8) + threadIdx.x;
  int p = tile / 5, f = tile % 5;
  const float* src = part + ((size_t)(p * 5 + f) * NCHUNK) * 16384 + e;
  float s = 0.f;
  #pragma unroll
  for (int c = 0; c < NCHUNK; ++c) s += src[(size_t)c * 16384];
  int rr = e >> 7, cc = e & 127;
  int i0 = c_pA[p], j0 = c_pB[p];
  if (p < 10) xxT[(size_t)f * DIM * DIM + (i0 + rr) * DIM + (j0 + cc)] = s;
  else        xyT[(size_t)f * ODIM * DIM + (i0 - 512 + rr) * DIM + (j0 + cc)] = s;
}

// ---------- train means (5 LOO + full) ----------
__global__ void k_means(const float* __restrict__ sumX_f, const float* __restrict__ sumY_f,
                        float* __restrict__ muX, float* __restrict__ muY) {
  int g = blockIdx.x * 256 + threadIdx.x;
  if (g < 6 * DIM) {
    int k = g / DIM, d = g % DIM;
    float s = 0.f;
    #pragma unroll
    for (int kk = 0; kk < 5; ++kk) s += sumX_f[kk * DIM + d];
    muX[g] = (k < 5) ? (s - sumX_f[k * DIM + d]) / (float)NTR : s / (float)NROWS;
  } else {
    int g2 = g - 6 * DIM;
    int k = g2 / ODIM, o = g2 % ODIM;
    float s = 0.f;
    #pragma unroll
    for (int kk = 0; kk < 5; ++kk) s += sumY_f[kk * ODIM + o];
    muY[g2] = (k < 5) ? (s - sumY_f[k * ODIM + o]) / (float)NTR : s / (float)NROWS;
  }
}

// ---------- assemble A_k (bf16) + Gv (bf16); xxT stored upper-tri, mirror on read ----------
__global__ void k_asmA(const float* __restrict__ xxT, const float* __restrict__ muX,
                       unsigned short* __restrict__ Abf, unsigned short* __restrict__ Gv) {
  size_t g = (size_t)blockIdx.x * 256 + threadIdx.x;     // < 6*512*512
  int k = (int)(g / (DIM * DIM));
  int r = (int)(g % (DIM * DIM));
  int d = r / DIM, e = r % DIM;
  int ridx = (d <= e) ? r : (e * DIM + d);
  float s = 0.f;
  #pragma unroll
  for (int kk = 0; kk < 5; ++kk) s += xxT[(size_t)kk * DIM * DIM + ridx];
  float v;
  if (k < 5) {
    float own = xxT[(size_t)k * DIM * DIM + ridx];
    v = s - own - (float)NTR * muX[k * DIM + d] * muX[k * DIM + e];
    Gv[(size_t)k * DIM * DIM + r] = f2bf(own);
  } else {
    v = s - (float)NROWS * muX[5 * DIM + d] * muX[5 * DIM + e];
  }
  Abf[g] = f2bf(v);
}

// ---------- assemble B_k^T [k][o][d] f32 and init x0 for all 30 systems ----------
__global__ void k_asmB(const float* __restrict__ xyT, const float* __restrict__ muX,
                       const float* __restrict__ muY, float* __restrict__ BT,
                       unsigned short* __restrict__ x0) {
  int g = blockIdx.x * 256 + threadIdx.x;                // < 6*256*512
  int k = g / (ODIM * DIM);
  int r = g % (ODIM * DIM);
  int o = r / DIM, d = r % DIM;
  float s = 0.f;
  #pragma unroll
  for (int kk = 0; kk < 5; ++kk) s += xyT[(size_t)kk * ODIM * DIM + r];
  float v;
  if (k < 5) v = s - xyT[(size_t)k * ODIM * DIM + r] - (float)NTR * muY[k * ODIM + o] * muX[k * DIM + d];
  else       v = s - (float)NROWS * muY[5 * ODIM + o] * muX[5 * DIM + d];
  BT[g] = v;
  float halfsum = (k < 5) ? 40750.f : 50750.f;           // (a+b)/2 spectral midpoint
  #pragma unroll
  for (int l = 0; l < 5; ++l) {
    float th = halfsum + c_lam[l];
    x0[(size_t)(l * 6 + k) * (ODIM * DIM) + r] = f2bf(v / th);
  }
}

// ---------- one Richardson sweep; k5only=1 restricts to the 5 full-data systems ----------
__global__ __launch_bounds__(256, 2) void k_rich(const unsigned short* __restrict__ xin,
                                                 unsigned short* __restrict__ xout,
                                                 const unsigned short* __restrict__ Abf,
                                                 const float* __restrict__ BT,
                                                 int k5only) {
  __shared__ unsigned short Xb[128][64];
  __shared__ unsigned short Mb[128][64];
  int tile = blockIdx.x;
  int o0 = (tile & 1) * 128, d0 = (tile >> 1) * 128;
  int s = k5only ? (blockIdx.y * 6 + 5) : blockIdx.y;
  int k = s % 6, l = s / 6;
  float lam = c_lam[l];
  float absum = (k < 5) ? 81500.f : 101500.f;
  float alpha = 2.f / (absum + 2.f * lam);
  const unsigned short* xs = xin + (size_t)s * ODIM * DIM;
  const unsigned short* Am = Abf + (size_t)k * DIM * DIM;
  int t = threadIdx.x, lane = t & 63, w = t >> 6;
  int wm = (w & 1) * 64, wn = (w >> 1) * 64;
  int srow = w * 32 + (lane >> 3);
  int scol = ((lane & 7) ^ (lane >> 3)) * 8;
  const unsigned short* gX = xs + (size_t)(o0 + srow) * DIM + scol;
  const unsigned short* gM = Am + (size_t)(d0 + srow) * DIM + scol;
  floatx4 acc[4][4];
  #pragma unroll
  for (int a = 0; a < 4; ++a)
    #pragma unroll
    for (int b = 0; b < 4; ++b) acc[a][b] = (floatx4)0.f;
  for (int ks = 0; ks < DIM; ks += 64) {
    #pragma unroll
    for (int q = 0; q < 4; ++q) {
      gload_lds(gX + (size_t)q * 8 * DIM, &Xb[w * 32 + q * 8][0]);
      gload_lds(gM + (size_t)q * 8 * DIM, &Mb[w * 32 + q * 8][0]);
    }
    gX += 64; gM += 64;
    __syncthreads();
    mfma_step(Xb, Mb, wm, wn, lane, acc);
    __syncthreads();
  }
  const float* Bk = BT + (size_t)k * ODIM * DIM;
  unsigned short* xo = xout + (size_t)s * ODIM * DIM;
  #pragma unroll
  for (int mt = 0; mt < 4; ++mt)
    #pragma unroll
    for (int nt = 0; nt < 4; ++nt)
      #pragma unroll
      for (int i = 0; i < 4; ++i) {
        int ro = o0 + wm + mt * 16 + ((lane >> 4) * 4 + i);
        int cd = d0 + wn + nt * 16 + (lane & 15);
        int idx = ro * DIM + cd;
        float xold = bf2f(xs[idx]);
        float r = Bk[idx] - acc[mt][nt][i] - lam * xold;
        xo[idx] = f2bf(xold + alpha * r);
      }
}

// ---------- tr(W^T Gv W) via GEMM + dot, atomic per (l,k) ----------
__global__ __launch_bounds__(256, 2) void k_loss_big(const unsigned short* __restrict__ x,
                                                     const unsigned short* __restrict__ Gv,
                                                     float* __restrict__ SSEb) {
  __shared__ unsigned short Xb[128][64];
  __shared__ unsigned short Mb[128][64];
  int tile = blockIdx.x;
  int o0 = (tile & 1) * 128, d0 = (tile >> 1) * 128;
  int s25 = blockIdx.y;
  int k = s25 % 5, l = s25 / 5;
  int s = l * 6 + k;
  const unsigned short* xs = x + (size_t)s * ODIM * DIM;
  const unsigned short* Gm = Gv + (size_t)k * DIM * DIM;
  int t = threadIdx.x, lane = t & 63, w = t >> 6;
  int wm = (w & 1) * 64, wn = (w >> 1) * 64;
  int srow = w * 32 + (lane >> 3);
  int scol = ((lane & 7) ^ (lane >> 3)) * 8;
  const unsigned short* gX = xs + (size_t)(o0 + srow) * DIM + scol;
  const unsigned short* gM = Gm + (size_t)(d0 + srow) * DIM + scol;
  floatx4 acc[4][4];
  #pragma unroll
  for (int a = 0; a < 4; ++a)
    #pragma unroll
    for (int b = 0; b < 4; ++b) acc[a][b] = (floatx4)0.f;
  for (int ks = 0; ks < DIM; ks += 64) {
    #pragma unroll
    for (int q = 0; q < 4; ++q) {
      gload_lds(gX + (size_t)q * 8 * DIM, &Xb[w * 32 + q * 8][0]);
      gload_lds(gM + (size_t)q * 8 * DIM, &Mb[w * 32 + q * 8][0]);
    }
    gX += 64; gM += 64;
    __syncthreads();
    mfma_step(Xb, Mb, wm, wn, lane, acc);
    __syncthreads();
  }
  float part = 0.f;
  #pragma unroll
  for (int mt = 0; mt < 4; ++mt)
    #pragma unroll
    for (int nt = 0; nt < 4; ++nt)
      #pragma unroll
      for (int i = 0; i < 4; ++i) {
        int ro = o0 + wm + mt * 16 + ((lane >> 4) * 4 + i);
        int cd = d0 + wn + nt * 16 + (lane & 15);
        part += acc[mt][nt][i] * bf2f(xs[ro * DIM + cd]);
      }
  float tot = block_sum256(part);
  if (threadIdx.x == 0) atomicAdd(&SSEb[s25], tot);
}

// ---------- linear/const SSE terms per (l,k); grid (25,8), 32 o-rows per block ----------
__global__ __launch_bounds__(256) void k_loss_small(const unsigned short* __restrict__ x,
                                                    const float* __restrict__ xyT,
                                                    const float* __restrict__ muX,
                                                    const float* __restrict__ muY,
                                                    const float* __restrict__ sumX_f,
                                                    const float* __restrict__ sumY_f,
                                                    float* __restrict__ SSEs) {
  __shared__ float lmu[DIM];
  __shared__ float lsx[DIM];
  int s25 = blockIdx.x, oc = blockIdx.y;
  int k = s25 % 5, l = s25 / 5;
  int sidx = l * 6 + k;
  int t = threadIdx.x;
  lmu[t] = muX[k * DIM + t];       lmu[t + 256] = muX[k * DIM + t + 256];
  lsx[t] = sumX_f[k * DIM + t];    lsx[t + 256] = sumX_f[k * DIM + t + 256];
  __syncthreads();
  int o = oc * 32 + (t >> 3);
  int ds = (t & 7) * 64;
  const unsigned short* xr = x + (size_t)sidx * ODIM * DIM + (size_t)o * DIM + ds;
  const float* cv = xyT + (size_t)k * ODIM * DIM + (size_t)o * DIM + ds;
  float t1 = 0.f, t2 = 0.f, trc = 0.f;
  #pragma unroll 4
  for (int d = 0; d < 64; d += 4) {
    ushort4 xv = *(const ushort4*)(xr + d);
    float4 cf = *(const float4*)(cv + d);
    float a0 = bf2f(xv.x), a1 = bf2f(xv.y), a2 = bf2f(xv.z), a3 = bf2f(xv.w);
    int dd = ds + d;
    t1 += a0 * lsx[dd] + a1 * lsx[dd + 1] + a2 * lsx[dd + 2] + a3 * lsx[dd + 3];
    t2 += a0 * lmu[dd] + a1 * lmu[dd + 1] + a2 * lmu[dd + 2] + a3 * lmu[dd + 3];
    trc += a0 * cf.x + a1 * cf.y + a2 * cf.z + a3 * cf.w;
  }
  for (int off = 4; off; off >>= 1) {
    t1 += __shfl_down(t1, off, 64);
    t2 += __shfl_down(t2, off, 64);
    trc += __shfl_down(trc, off, 64);
  }
  float part = 0.f;
  if ((t & 7) == 0) {
    float b = muY[k * ODIM + o] - t2;
    float syv = sumY_f[k * ODIM + o];
    part = 2.f * b * t1 + (float)FOLD * b * b - 2.f * trc - 2.f * b * syv;
  }
  float tot = block_sum256(part);
  if (t == 0) atomicAdd(&SSEs[s25], tot);
}

// ---------- losses + argmin ----------
__global__ void k_loss_final(const float* __restrict__ SSEs, const float* __restrict__ SSEb,
                             const float* __restrict__ yy_f,
                             float* __restrict__ out, int* __restrict__ aidx) {
  if (threadIdx.x == 0) {
    float best = 1e30f; int bi = 0;
    for (int l = 0; l < 5; ++l) {
      float s = 0.f;
      for (int k = 0; k < 5; ++k) s += SSEs[l * 5 + k] + SSEb[l * 5 + k] + yy_f[k];
      float loss = s / (float)(FOLDS * FOLD * ODIM);
      out[131072 + 256 + l] = loss;
      if (loss < best) { best = loss; bi = l; }
    }
    aidx[0] = bi;
  }
}

// ---------- outputs ----------
__global__ void k_outW(const unsigned short* __restrict__ x, const int* __restrict__ aidx,
                       float* __restrict__ out) {
  int g = blockIdx.x * 256 + threadIdx.x;
  int s = aidx[0] * 6 + 5;
  out[g] = bf2f(x[(size_t)s * ODIM * DIM + g]);
}

__global__ __launch_bounds__(64) void k_outB(const unsigned short* __restrict__ x,
                                             const float* __restrict__ muX,
                                             const float* __restrict__ muY,
                                             const int* __restrict__ aidx,
                                             float* __restrict__ out) {
  int o = blockIdx.x, lane = threadIdx.x;
  int s = aidx[0] * 6 + 5;
  const unsigned short* xr = x + (size_t)s * ODIM * DIM + (size_t)o * DIM;
  float dsum = 0.f;
  for (int d = lane; d < DIM; d += 64) dsum += bf2f(xr[d]) * muX[5 * DIM + d];
  for (int off = 32; off; off >>= 1) dsum += __shfl_down(dsum, off, 64);
  if (lane == 0) out[131072 + o] = muY[5 * ODIM + o] - dsum;
}

extern "C" void kernel_launch(void* const* d_in, const int* in_sizes, int n_in,
                              void* d_out, int out_size, void* d_ws, size_t ws_size,
                              hipStream_t stream) {
  const float* X = (const float*)d_in[0];
  const float* Y = (const float*)d_in[1];
  float* out = (float*)d_out;
  char* ws = (char*)d_ws;
  size_t off = 0;
  auto alloc = [&](size_t bytes) {
    size_t cur = off;
    off = (off + bytes + 255) & ~(size_t)255;
    return cur;
  };
  unsigned short* ZT = (unsigned short*)(ws + alloc((size_t)768 * ZROW * 2));
  float* xxT    = (float*)(ws + alloc((size_t)5 * DIM * DIM * 4));
  float* xyT    = (float*)(ws + alloc((size_t)5 * ODIM * DIM * 4));
  float* sumX_f = (float*)(ws + alloc(5 * DIM * 4));
  float* muX    = (float*)(ws + alloc(6 * DIM * 4));
  float* muY    = (float*)(ws + alloc(6 * ODIM * 4));
  int* aidx     = (int*)(ws + alloc(4));
  size_t zbeg = off;
  float* sumY_f = (float*)(ws + alloc(5 * ODIM * 4));
  float* yy_f   = (float*)(ws + alloc(5 * 4));
  float* SSEb   = (float*)(ws + alloc(25 * 4));
  float* SSEs   = (float*)(ws + alloc(25 * 4));
  size_t zend = off;
  // union region: partial tiles (29.5 MB) reused later by Abf/Gv/BT/x0/x1 (24.7 MB)
  char* ub = ws + alloc((size_t)18 * 5 * NCHUNK * 16384 * 4);
  float* part = (float*)ub;
  unsigned short* Abf = (unsigned short*)ub;
  unsigned short* Gv  = Abf + (size_t)6 * DIM * DIM;
  float* BT           = (float*)(Gv + (size_t)5 * DIM * DIM);
  unsigned short* x0  = (unsigned short*)(BT + (size_t)6 * ODIM * DIM);
  unsigned short* x1  = x0 + (size_t)30 * ODIM * DIM;

  hipMemsetAsync(ws + zbeg, 0, zend - zbeg, stream);

  k_padZ<<<768, 256, 0, stream>>>(ZT);
  k_tXY<<<dim3(782, 12), 256, 0, stream>>>(X, Y, ZT);
  k_sumX<<<5 * DIM, 64, 0, stream>>>(ZT, sumX_f);
  k_sumY<<<dim3(5, 125), 256, 0, stream>>>(Y, sumY_f, yy_f);
  k_gram<<<dim3(18, 5, NCHUNK), 256, 0, stream>>>(ZT, part);
  k_red<<<18 * 5 * 64, 256, 0, stream>>>(part, xxT, xyT);
  k_means<<<18, 256, 0, stream>>>(sumX_f, sumY_f, muX, muY);
  k_asmA<<<6 * DIM * DIM / 256, 256, 0, stream>>>(xxT, muX, Abf, Gv);
  k_asmB<<<6 * ODIM * DIM / 256, 256, 0, stream>>>(xyT, muX, muY, BT, x0);
  // 3 sweeps over all 30 systems + 1 over the 5 full-data (k=5) systems.
  // CV final state in x1; full-data final state in x0.
  k_rich<<<dim3(8, 30), 256, 0, stream>>>(x0, x1, Abf, BT, 0);
  k_rich<<<dim3(8, 30), 256, 0, stream>>>(x1, x0, Abf, BT, 0);
  k_rich<<<dim3(8, 30), 256, 0, stream>>>(x0, x1, Abf, BT, 0);
  k_rich<<<dim3(8, 5),  256, 0, stream>>>(x1, x0, Abf, BT, 1);
  k_loss_small<<<dim3(25, 8), 256, 0, stream>>>(x1, xyT, muX, muY, sumX_f, sumY_f, SSEs);
  k_loss_big<<<dim3(8, 25), 256, 0, stream>>>(x1, Gv, SSEb);
  k_loss_final<<<1, 64, 0, stream>>>(SSEs, SSEb, yy_f, out, aidx);
  k_outW<<<DIM * ODIM / 256, 256, 0, stream>>>(x0, aidx, out);
  k_outB<<<ODIM, 64, 0, stream>>>(x0, muX, muY, aidx, out);
}